// Round 14
// baseline (100.703 us; speedup 1.0000x reference)
//
#include <hip/hip_runtime.h>
#include <hip/hip_fp16.h>
#include <math.h>

#define BB 16
#define NN 1024
#define DD 768
#define KK 8
#define BETA_F 0.5f
#define EPS_F 1e-8f

#define TPK_BLOCKS ((BB * NN) / 8)         // 2048: 4 waves/block x 2 points/wave
#define NORM2_BLOCKS ((BB * NN) / 8)       // 2048: 4 waves/block x 2 rows/wave
#define LOSS_BLOCKS ((BB * NN) / 4)        // 4096

typedef _Float16 h2_t __attribute__((ext_vector_type(2)));

#if defined(__has_builtin)
#if __has_builtin(__builtin_amdgcn_fdot2)
#define HAVE_FDOT2 1
#endif
#endif

// acc += dot of 4 halves packed in uint2 (v_dot2_f32_f16 x2, or unpack-fma fallback)
__device__ __forceinline__ float dot4acc(uint2 a, uint2 b, float acc) {
#ifdef HAVE_FDOT2
    acc = __builtin_amdgcn_fdot2(__builtin_bit_cast(h2_t, a.x),
                                 __builtin_bit_cast(h2_t, b.x), acc, false);
    acc = __builtin_amdgcn_fdot2(__builtin_bit_cast(h2_t, a.y),
                                 __builtin_bit_cast(h2_t, b.y), acc, false);
#else
    float2 fa = __half22float2(__builtin_bit_cast(__half2, a.x));
    float2 fb = __half22float2(__builtin_bit_cast(__half2, b.x));
    acc = fmaf(fa.x, fb.x, acc); acc = fmaf(fa.y, fb.y, acc);
    fa = __half22float2(__builtin_bit_cast(__half2, a.y));
    fb = __half22float2(__builtin_bit_cast(__half2, b.y));
    acc = fmaf(fa.x, fb.x, acc); acc = fmaf(fa.y, fb.y, acc);
#endif
    return acc;
}

// ---------------------------------------------------------------------------
// Wave-wide u32 min via DPP (VALU pipe). Proven rounds 11-13.
// ---------------------------------------------------------------------------
__device__ __forceinline__ unsigned wave_min_u32_to_all(unsigned x) {
    int v = (int)x;
#define STEP(CTRL, RM) {                                                    \
        int y_ = __builtin_amdgcn_update_dpp(v, v, CTRL, RM, 0xf, false);   \
        v = (int)((unsigned)v < (unsigned)y_ ? (unsigned)v : (unsigned)y_); \
    }
    STEP(0x111, 0xf)   // row_shr:1
    STEP(0x112, 0xf)   // row_shr:2
    STEP(0x114, 0xf)   // row_shr:4
    STEP(0x118, 0xf)   // row_shr:8
    STEP(0x142, 0xa)   // row_bcast:15 -> rows 1,3
    STEP(0x143, 0xc)   // row_bcast:31 -> rows 2,3
#undef STEP
    return (unsigned)__builtin_amdgcn_readlane(v, 63);
}

// ---------------------------------------------------------------------------
// topk: EXACT round-11 code (best measured: 53 us fused). u32 two-phase:
// DPP min for the value, 16x ballot + SALU chain for the location (SALU
// co-issues next to the other point's VALU work — r13 proved replacing it
// with a second DPP chain regresses). Two points per wave. Full unroll.
// ---------------------------------------------------------------------------
__device__ __forceinline__ unsigned topk_u(float anx, float any_, float sqn, float4 c) {
    float dot = anx * c.x + any_ * c.y;
    float d2  = (sqn + c.z) - 2.0f * dot;
    unsigned int u = __float_as_uint(d2);
    u ^= (unsigned int)((int)u >> 31) | 0x80000000u;
    return u;
}

struct KeysU { unsigned k[16]; };

#define PIN_KEYSU(K)                                                        \
    asm("" : "+v"(K.k[0]),  "+v"(K.k[1]),  "+v"(K.k[2]),  "+v"(K.k[3]),    \
             "+v"(K.k[4]),  "+v"(K.k[5]),  "+v"(K.k[6]),  "+v"(K.k[7]),    \
             "+v"(K.k[8]),  "+v"(K.k[9]),  "+v"(K.k[10]), "+v"(K.k[11]),   \
             "+v"(K.k[12]), "+v"(K.k[13]), "+v"(K.k[14]), "+v"(K.k[15]))

__device__ __forceinline__ void initkeysu(KeysU& K, float anx, float any_, float sqn,
                                          const float4* c4, int lane) {
#pragma unroll
    for (int i = 0; i < 16; ++i) {
        const int m_ = i * 64 + lane;
        K.k[i] = topk_u(anx, any_, sqn, c4[m_]);
    }
}

__device__ __forceinline__ unsigned umin2(unsigned a, unsigned b) { return a < b ? a : b; }

__device__ __forceinline__ unsigned mintreeu(const KeysU& K) {
    return umin2(umin2(umin2(umin2(K.k[0], K.k[1]),  umin2(K.k[2], K.k[3])),
                       umin2(umin2(K.k[4], K.k[5]),  umin2(K.k[6], K.k[7]))),
                 umin2(umin2(umin2(K.k[8], K.k[9]),  umin2(K.k[10], K.k[11])),
                       umin2(umin2(K.k[12], K.k[13]), umin2(K.k[14], K.k[15]))));
}

__device__ __forceinline__ void topk_wave_body(const float* __restrict__ centers,
                                               int* __restrict__ idx_out,
                                               int tb, int tid, float4* c4) {
    const int b    = tb >> 7;          // 128 topk blocks per batch
    const int grp  = tb & 127;
    const int wave = tid >> 6;
    const int lane = tid & 63;

    // stage packed (x, y, x^2+y^2) — identical arithmetic to prior rounds
    const float4* cbase = (const float4*)(centers + (size_t)b * NN * 2);
    for (int i = tid; i < NN / 2; i += 256) {
        float4 v = cbase[i];
        c4[2 * i + 0] = make_float4(v.x, v.y, v.x * v.x + v.y * v.y, 0.f);
        c4[2 * i + 1] = make_float4(v.z, v.w, v.z * v.z + v.w * v.w, 0.f);
    }
    __syncthreads();

    const int nA = grp * 8 + wave * 2;   // two points per wave
    const int nB = nA + 1;
    const float4 cA = c4[nA];
    const float4 cB = c4[nB];

    KeysU KA, KB;
    initkeysu(KA, cA.x, cA.y, cA.z, c4, lane);
    initkeysu(KB, cB.x, cB.y, cB.z, c4, lane);
    PIN_KEYSU(KA);
    PIN_KEYSU(KB);

    unsigned lmA = mintreeu(KA);
    unsigned lmB = mintreeu(KB);
    int mmA[9], mmB[9];

#pragma unroll
    for (int r = 0; r < 9; ++r) {
        const unsigned gA = wave_min_u32_to_all(lmA);
        const unsigned gB = wave_min_u32_to_all(lmB);

        // phase 2: min m among keys equal to g (ballot -> SALU chain)
        unsigned mA = 0xffffffffu, mB = 0xffffffffu;
#pragma unroll
        for (int i = 15; i >= 0; --i) {
            unsigned long long bA = __ballot(KA.k[i] == gA);
            unsigned long long bB = __ballot(KB.k[i] == gB);
            mA = bA ? (unsigned)(i * 64) + (unsigned)__builtin_ctzll(bA) : mA;
            mB = bB ? (unsigned)(i * 64) + (unsigned)__builtin_ctzll(bB) : mB;
        }
        mmA[r] = (int)mA;
        mmB[r] = (int)mB;

        // kill exactly the winning (i, lane) key
        const unsigned iwA = mA >> 6, lwA = mA & 63;
        const unsigned iwB = mB >> 6, lwB = mB & 63;
        const bool winA = ((unsigned)lane == lwA);
        const bool winB = ((unsigned)lane == lwB);
#pragma unroll
        for (int i = 0; i < 16; ++i) {
            KA.k[i] = ((unsigned)i == iwA && winA) ? 0xffffffffu : KA.k[i];
            KB.k[i] = ((unsigned)i == iwB && winB) ? 0xffffffffu : KB.k[i];
        }
        PIN_KEYSU(KA);
        PIN_KEYSU(KB);
        lmA = mintreeu(KA);
        lmB = mintreeu(KB);
    }

    if (lane == 0) {
        int* outp = idx_out + ((size_t)b * NN + nA) * KK;   // nB rows follow
        ((int4*)outp)[0] = make_int4(mmA[1], mmA[2], mmA[3], mmA[4]);
        ((int4*)outp)[1] = make_int4(mmA[5], mmA[6], mmA[7], mmA[8]);
        ((int4*)outp)[2] = make_int4(mmB[1], mmB[2], mmB[3], mmB[4]);
        ((int4*)outp)[3] = make_int4(mmB[5], mmB[6], mmB[7], mmB[8]);
    }
}

// standalone topk dispatch (f32 fallback path)
__global__ __launch_bounds__(256) void topk_kernel(const float* __restrict__ centers,
                                                   int* __restrict__ idx_out) {
    __shared__ float4 c4[NN];
    topk_wave_body(centers, idx_out, blockIdx.x, threadIdx.x, c4);
}

// ---------------------------------------------------------------------------
// normh2: row-normalize s,t -> fp16, TWO rows per wave (the single change
// this round vs r11). r12 standalone counters: 1-row normh = 40 us @ 2.5 TB/s,
// VALUBusy 9% -> latency-bound on one serial reduce chain. 12 loads issued up
// front, 4 independent chains interleaved. Per-row fma/reduce order identical
// to rounds 6-13 -> ns/nt bit-identical.
// ---------------------------------------------------------------------------
__device__ __forceinline__ void normh2_body(const float* __restrict__ s,
                                            const float* __restrict__ t,
                                            __half* __restrict__ ns,
                                            __half* __restrict__ nt,
                                            int nb, int tid) {
    const int wave = tid >> 6;
    const int lane = tid & 63;
    const int row0 = nb * 8 + wave * 2;
    const int row1 = row0 + 1;
    const float4* s0 = (const float4*)(s + (size_t)row0 * DD);
    const float4* t0 = (const float4*)(t + (size_t)row0 * DD);
    const float4* s1 = (const float4*)(s + (size_t)row1 * DD);
    const float4* t1 = (const float4*)(t + (size_t)row1 * DD);

    float4 vs0[3], vt0[3], vs1[3], vt1[3];
#pragma unroll
    for (int i = 0; i < 3; ++i) {
        vs0[i] = s0[lane + 64 * i];
        vt0[i] = t0[lane + 64 * i];
        vs1[i] = s1[lane + 64 * i];
        vt1[i] = t1[lane + 64 * i];
    }
    float ss0 = 0.f, tt0 = 0.f, ss1 = 0.f, tt1 = 0.f;
#pragma unroll
    for (int i = 0; i < 3; ++i) {
        ss0 = fmaf(vs0[i].x, vs0[i].x, fmaf(vs0[i].y, vs0[i].y,
              fmaf(vs0[i].z, vs0[i].z, fmaf(vs0[i].w, vs0[i].w, ss0))));
        tt0 = fmaf(vt0[i].x, vt0[i].x, fmaf(vt0[i].y, vt0[i].y,
              fmaf(vt0[i].z, vt0[i].z, fmaf(vt0[i].w, vt0[i].w, tt0))));
        ss1 = fmaf(vs1[i].x, vs1[i].x, fmaf(vs1[i].y, vs1[i].y,
              fmaf(vs1[i].z, vs1[i].z, fmaf(vs1[i].w, vs1[i].w, ss1))));
        tt1 = fmaf(vt1[i].x, vt1[i].x, fmaf(vt1[i].y, vt1[i].y,
              fmaf(vt1[i].z, vt1[i].z, fmaf(vt1[i].w, vt1[i].w, tt1))));
    }
#pragma unroll
    for (int m = 1; m < 64; m <<= 1) {
        ss0 += __shfl_xor(ss0, m);
        tt0 += __shfl_xor(tt0, m);
        ss1 += __shfl_xor(ss1, m);
        tt1 += __shfl_xor(tt1, m);
    }
    const float is0 = 1.0f / fmaxf(sqrtf(ss0), EPS_F);
    const float it0 = 1.0f / fmaxf(sqrtf(tt0), EPS_F);
    const float is1 = 1.0f / fmaxf(sqrtf(ss1), EPS_F);
    const float it1 = 1.0f / fmaxf(sqrtf(tt1), EPS_F);

    uint2* ns0 = (uint2*)(ns + (size_t)row0 * DD);
    uint2* nt0 = (uint2*)(nt + (size_t)row0 * DD);
    uint2* ns1 = (uint2*)(ns + (size_t)row1 * DD);
    uint2* nt1 = (uint2*)(nt + (size_t)row1 * DD);
#pragma unroll
    for (int i = 0; i < 3; ++i) {
        __half2 a0 = __floats2half2_rn(vs0[i].x * is0, vs0[i].y * is0);
        __half2 a1 = __floats2half2_rn(vs0[i].z * is0, vs0[i].w * is0);
        __half2 b0 = __floats2half2_rn(vt0[i].x * it0, vt0[i].y * it0);
        __half2 b1 = __floats2half2_rn(vt0[i].z * it0, vt0[i].w * it0);
        __half2 c0 = __floats2half2_rn(vs1[i].x * is1, vs1[i].y * is1);
        __half2 c1 = __floats2half2_rn(vs1[i].z * is1, vs1[i].w * is1);
        __half2 d0 = __floats2half2_rn(vt1[i].x * it1, vt1[i].y * it1);
        __half2 d1 = __floats2half2_rn(vt1[i].z * it1, vt1[i].w * it1);
        uint2 ua, ub, uc, ud;
        ua.x = __builtin_bit_cast(unsigned int, a0); ua.y = __builtin_bit_cast(unsigned int, a1);
        ub.x = __builtin_bit_cast(unsigned int, b0); ub.y = __builtin_bit_cast(unsigned int, b1);
        uc.x = __builtin_bit_cast(unsigned int, c0); uc.y = __builtin_bit_cast(unsigned int, c1);
        ud.x = __builtin_bit_cast(unsigned int, d0); ud.y = __builtin_bit_cast(unsigned int, d1);
        ns0[lane + 64 * i] = ua;
        nt0[lane + 64 * i] = ub;
        ns1[lane + 64 * i] = uc;
        nt1[lane + 64 * i] = ud;
    }
}

// ---------------------------------------------------------------------------
// Fused kernel: 1:1 interleave (bid&1), 2048 topk + 2048 normh2 blocks.
// ---------------------------------------------------------------------------
__global__ __launch_bounds__(256) void fused_prep(const float* __restrict__ centers,
                                                  const float* __restrict__ s,
                                                  const float* __restrict__ t,
                                                  int* __restrict__ idx_out,
                                                  __half* __restrict__ ns,
                                                  __half* __restrict__ nt) {
    __shared__ float4 c4[NN];                 // 16 KB
    if (blockIdx.x & 1)
        normh2_body(s, t, ns, nt, blockIdx.x >> 1, threadIdx.x);
    else
        topk_wave_body(centers, idx_out, blockIdx.x >> 1, threadIdx.x, c4);
}

// ---------------------------------------------------------------------------
// lossh: gather normalized fp16 rows, dot -> cosines, smooth-L1, per-block
// partial. XCD batch-affinity swizzle. (unchanged from rounds 6-13)
// ---------------------------------------------------------------------------
__global__ __launch_bounds__(256) void lossh_kernel(const __half* __restrict__ ns,
                                                    const __half* __restrict__ nt,
                                                    const int* __restrict__ idx,
                                                    float* __restrict__ part) {
    const int bid  = blockIdx.x;
    const int v    = (bid & 7) * 512 + (bid >> 3);   // bijective, nwg%8==0
    const int wave = threadIdx.x >> 6;
    const int lane = threadIdx.x & 63;
    const int p    = v * 4 + wave;
    const int base = p & ~(NN - 1);

    int q[8];
    {
        const int4* ip = (const int4*)(idx + (size_t)p * KK);
        int4 a = ip[0], c = ip[1];
        q[0] = base + a.x; q[1] = base + a.y; q[2] = base + a.z; q[3] = base + a.w;
        q[4] = base + c.x; q[5] = base + c.y; q[6] = base + c.z; q[7] = base + c.w;
    }

    const uint2* srow = (const uint2*)(ns + (size_t)p * DD);
    const uint2* trow = (const uint2*)(nt + (size_t)p * DD);
    uint2 sa[3], ta[3];
#pragma unroll
    for (int c = 0; c < 3; ++c) {
        sa[c] = srow[lane + 64 * c];
        ta[c] = trow[lane + 64 * c];
    }

    uint2 sv[8][3], tv[8][3];
#pragma unroll
    for (int j = 0; j < 8; ++j) {
        const uint2* snb = (const uint2*)(ns + (size_t)q[j] * DD);
        const uint2* tnb = (const uint2*)(nt + (size_t)q[j] * DD);
#pragma unroll
        for (int c = 0; c < 3; ++c) {
            sv[j][c] = snb[lane + 64 * c];
            tv[j][c] = tnb[lane + 64 * c];
        }
    }

    float ds[8], dt[8];
#pragma unroll
    for (int j = 0; j < 8; ++j) {
        float a = 0.f, b = 0.f;
#pragma unroll
        for (int c = 0; c < 3; ++c) {
            a = dot4acc(sa[c], sv[j][c], a);
            b = dot4acc(ta[c], tv[j][c], b);
        }
        ds[j] = a;
        dt[j] = b;
    }
#pragma unroll
    for (int m = 1; m < 64; m <<= 1) {
#pragma unroll
        for (int j = 0; j < 8; ++j) {
            ds[j] += __shfl_xor(ds[j], m);
            dt[j] += __shfl_xor(dt[j], m);
        }
    }
    float sum = 0.f;
#pragma unroll
    for (int j = 0; j < 8; ++j) {
        const float diff = fabsf(ds[j] - dt[j]);     // rows pre-normalized
        sum += diff < BETA_F ? (0.5f * diff * diff / BETA_F) : (diff - 0.5f * BETA_F);
    }

    __shared__ float wpart[4];
    if (lane == 0) wpart[wave] = sum;
    __syncthreads();
    if (threadIdx.x == 0)
        part[v] = (wpart[0] + wpart[1]) + (wpart[2] + wpart[3]);
}

// ---------------------------------------------------------------------------
// f32 fallback path (only if ws_size too small for fp16 copies).
// ---------------------------------------------------------------------------
__global__ __launch_bounds__(256) void norm_kernel(const float* __restrict__ s,
                                                   const float* __restrict__ t,
                                                   float* __restrict__ inv_s,
                                                   float* __restrict__ inv_t) {
    const int row  = blockIdx.x * 4 + (threadIdx.x >> 6);
    const int lane = threadIdx.x & 63;
    const float4* srow = (const float4*)(s + (size_t)row * DD);
    const float4* trow = (const float4*)(t + (size_t)row * DD);
    float ss = 0.f, tt = 0.f;
#pragma unroll
    for (int i = 0; i < 3; ++i) {
        float4 v = srow[lane + 64 * i];
        ss = fmaf(v.x, v.x, fmaf(v.y, v.y, fmaf(v.z, v.z, fmaf(v.w, v.w, ss))));
        float4 w = trow[lane + 64 * i];
        tt = fmaf(w.x, w.x, fmaf(w.y, w.y, fmaf(w.z, w.z, fmaf(w.w, w.w, tt))));
    }
#pragma unroll
    for (int m = 1; m < 64; m <<= 1) {
        ss += __shfl_xor(ss, m);
        tt += __shfl_xor(tt, m);
    }
    if (lane == 0) {
        inv_s[row] = 1.0f / fmaxf(sqrtf(ss), EPS_F);
        inv_t[row] = 1.0f / fmaxf(sqrtf(tt), EPS_F);
    }
}

__global__ __launch_bounds__(256) void lossf_kernel(const float* __restrict__ s,
                                                    const float* __restrict__ t,
                                                    const int* __restrict__ idx,
                                                    const float* __restrict__ inv_s,
                                                    const float* __restrict__ inv_t,
                                                    float* __restrict__ part) {
    const int wave = threadIdx.x >> 6;
    const int lane = threadIdx.x & 63;
    const int p    = blockIdx.x * 4 + wave;
    const int base = p & ~(NN - 1);
    int q[8];
    {
        const int4* ip = (const int4*)(idx + (size_t)p * KK);
        int4 a = ip[0], c = ip[1];
        q[0] = base + a.x; q[1] = base + a.y; q[2] = base + a.z; q[3] = base + a.w;
        q[4] = base + c.x; q[5] = base + c.y; q[6] = base + c.z; q[7] = base + c.w;
    }
    float isq[8], itq[8];
#pragma unroll
    for (int j = 0; j < 8; ++j) { isq[j] = inv_s[q[j]]; itq[j] = inv_t[q[j]]; }
    const float isn = inv_s[p];
    const float itn = inv_t[p];
    const float4* srow = (const float4*)(s + (size_t)p * DD);
    const float4* trow = (const float4*)(t + (size_t)p * DD);
    float4 as0 = srow[lane], as1 = srow[lane + 64], as2 = srow[lane + 128];
    float4 at0 = trow[lane], at1 = trow[lane + 64], at2 = trow[lane + 128];
    float ds[8], dt[8];
#pragma unroll
    for (int j = 0; j < 8; ++j) {
        const float4* snb = (const float4*)(s + (size_t)q[j] * DD);
        const float4* tnb = (const float4*)(t + (size_t)q[j] * DD);
        float4 v0 = snb[lane], v1 = snb[lane + 64], v2 = snb[lane + 128];
        float4 w0 = tnb[lane], w1 = tnb[lane + 64], w2 = tnb[lane + 128];
        float a = 0.f, b = 0.f;
        a = fmaf(as0.x, v0.x, a); a = fmaf(as0.y, v0.y, a);
        a = fmaf(as0.z, v0.z, a); a = fmaf(as0.w, v0.w, a);
        a = fmaf(as1.x, v1.x, a); a = fmaf(as1.y, v1.y, a);
        a = fmaf(as1.z, v1.z, a); a = fmaf(as1.w, v1.w, a);
        a = fmaf(as2.x, v2.x, a); a = fmaf(as2.y, v2.y, a);
        a = fmaf(as2.z, v2.z, a); a = fmaf(as2.w, v2.w, a);
        b = fmaf(at0.x, w0.x, b); b = fmaf(at0.y, w0.y, b);
        b = fmaf(at0.z, w0.z, b); b = fmaf(at0.w, w0.w, b);
        b = fmaf(at1.x, w1.x, b); b = fmaf(at1.y, w1.y, b);
        b = fmaf(at1.z, w1.z, b); b = fmaf(at1.w, w1.w, b);
        b = fmaf(at2.x, w2.x, b); b = fmaf(at2.y, w2.y, b);
        b = fmaf(at2.z, w2.z, b); b = fmaf(at2.w, w2.w, b);
        ds[j] = a; dt[j] = b;
    }
#pragma unroll
    for (int m = 1; m < 64; m <<= 1) {
#pragma unroll
        for (int j = 0; j < 8; ++j) {
            ds[j] += __shfl_xor(ds[j], m);
            dt[j] += __shfl_xor(dt[j], m);
        }
    }
    float sum = 0.f;
#pragma unroll
    for (int j = 0; j < 8; ++j) {
        const float cs   = ds[j] * isn * isq[j];
        const float ct   = dt[j] * itn * itq[j];
        const float diff = fabsf(cs - ct);
        sum += diff < BETA_F ? (0.5f * diff * diff / BETA_F) : (diff - 0.5f * BETA_F);
    }
    __shared__ float wpart[4];
    if (lane == 0) wpart[wave] = sum;
    __syncthreads();
    if (threadIdx.x == 0)
        part[blockIdx.x] = (wpart[0] + wpart[1]) + (wpart[2] + wpart[3]);
}

// ---------------------------------------------------------------------------
// finalize: deterministic tree reduce of 4096 block partials + final scale.
// ---------------------------------------------------------------------------
__global__ __launch_bounds__(256) void finalize_kernel(const float* __restrict__ part,
                                                       float* __restrict__ out) {
    __shared__ float red[256];
    float acc = 0.f;
    for (int i = threadIdx.x; i < (BB * NN) / 4; i += 256) acc += part[i];
    red[threadIdx.x] = acc;
    __syncthreads();
    for (int off = 128; off > 0; off >>= 1) {
        if (threadIdx.x < off) red[threadIdx.x] += red[threadIdx.x + off];
        __syncthreads();
    }
    if (threadIdx.x == 0) out[0] = red[0] * (1.0f / (float)(BB * NN * KK));
}

extern "C" void kernel_launch(void* const* d_in, const int* in_sizes, int n_in,
                              void* d_out, int out_size, void* d_ws, size_t ws_size,
                              hipStream_t stream) {
    const float* student = (const float*)d_in[0];
    const float* teacher = (const float*)d_in[1];
    const float* centers = (const float*)d_in[2];
    float* out = (float*)d_out;

    const size_t idx_bytes  = (size_t)BB * NN * KK * sizeof(int);      // 512 KB
    const size_t half_bytes = (size_t)BB * NN * DD * sizeof(__half);   // 25.2 MB
    const size_t part_bytes = 4096 * sizeof(float);
    int* idx_buf = (int*)d_ws;

    if (ws_size >= idx_bytes + 2 * half_bytes + part_bytes) {
        __half* ns  = (__half*)((char*)d_ws + idx_bytes);
        __half* nt  = ns + (size_t)BB * NN * DD;
        float* part = (float*)((char*)d_ws + idx_bytes + 2 * half_bytes);
        fused_prep<<<TPK_BLOCKS + NORM2_BLOCKS, 256, 0, stream>>>(centers, student,
                                                                  teacher, idx_buf, ns, nt);
        lossh_kernel<<<LOSS_BLOCKS, 256, 0, stream>>>(ns, nt, idx_buf, part);
        finalize_kernel<<<1, 256, 0, stream>>>(part, out);
    } else {
        float* inv_s = (float*)((char*)d_ws + idx_bytes);
        float* inv_t = inv_s + BB * NN;
        float* part  = inv_t + BB * NN;
        topk_kernel<<<TPK_BLOCKS, 256, 0, stream>>>(centers, idx_buf);
        norm_kernel<<<LOSS_BLOCKS, 256, 0, stream>>>(student, teacher, inv_s, inv_t);
        lossf_kernel<<<LOSS_BLOCKS, 256, 0, stream>>>(student, teacher, idx_buf,
                                                      inv_s, inv_t, part);
        finalize_kernel<<<1, 256, 0, stream>>>(part, out);
    }
}

// Round 15
// 100.579 us; speedup vs baseline: 1.0012x; 1.0012x over previous
//
#include <hip/hip_runtime.h>
#include <hip/hip_fp16.h>
#include <math.h>

#define BB 16
#define NN 1024
#define DD 768
#define KK 8
#define BETA_F 0.5f
#define EPS_F 1e-8f

#define TPK_BLOCKS ((BB * NN) / 8)         // 2048: 4 waves/block x 2 points/wave
#define NORM2_BLOCKS ((BB * NN) / 8)       // 2048: 4 waves/block x 2 rows/wave
#define LOSS_BLOCKS ((BB * NN) / 4)        // 4096

typedef _Float16 h2_t __attribute__((ext_vector_type(2)));

#if defined(__has_builtin)
#if __has_builtin(__builtin_amdgcn_fdot2)
#define HAVE_FDOT2 1
#endif
#endif

// acc += dot of 4 halves packed in uint2 (v_dot2_f32_f16 x2, or unpack-fma fallback)
__device__ __forceinline__ float dot4acc(uint2 a, uint2 b, float acc) {
#ifdef HAVE_FDOT2
    acc = __builtin_amdgcn_fdot2(__builtin_bit_cast(h2_t, a.x),
                                 __builtin_bit_cast(h2_t, b.x), acc, false);
    acc = __builtin_amdgcn_fdot2(__builtin_bit_cast(h2_t, a.y),
                                 __builtin_bit_cast(h2_t, b.y), acc, false);
#else
    float2 fa = __half22float2(__builtin_bit_cast(__half2, a.x));
    float2 fb = __half22float2(__builtin_bit_cast(__half2, b.x));
    acc = fmaf(fa.x, fb.x, acc); acc = fmaf(fa.y, fb.y, acc);
    fa = __half22float2(__builtin_bit_cast(__half2, a.y));
    fb = __half22float2(__builtin_bit_cast(__half2, b.y));
    acc = fmaf(fa.x, fb.x, acc); acc = fmaf(fa.y, fb.y, acc);
#endif
    return acc;
}

// ---------------------------------------------------------------------------
// Wave-wide u32 min via DPP (VALU pipe). Proven rounds 11-13.
// ---------------------------------------------------------------------------
__device__ __forceinline__ unsigned wave_min_u32_to_all(unsigned x) {
    int v = (int)x;
#define STEP(CTRL, RM) {                                                    \
        int y_ = __builtin_amdgcn_update_dpp(v, v, CTRL, RM, 0xf, false);   \
        v = (int)((unsigned)v < (unsigned)y_ ? (unsigned)v : (unsigned)y_); \
    }
    STEP(0x111, 0xf)   // row_shr:1
    STEP(0x112, 0xf)   // row_shr:2
    STEP(0x114, 0xf)   // row_shr:4
    STEP(0x118, 0xf)   // row_shr:8
    STEP(0x142, 0xa)   // row_bcast:15 -> rows 1,3
    STEP(0x143, 0xc)   // row_bcast:31 -> rows 2,3
#undef STEP
    return (unsigned)__builtin_amdgcn_readlane(v, 63);
}

// ---------------------------------------------------------------------------
// topk: EXACT round-11 code (best measured: 53 us fused). u32 two-phase:
// DPP min for the value, 16x ballot + SALU chain for the location (SALU
// co-issues next to the other point's VALU work — r13 proved replacing it
// with a second DPP chain regresses). Two points per wave. Full unroll.
// ---------------------------------------------------------------------------
__device__ __forceinline__ unsigned topk_u(float anx, float any_, float sqn, float4 c) {
    float dot = anx * c.x + any_ * c.y;
    float d2  = (sqn + c.z) - 2.0f * dot;
    unsigned int u = __float_as_uint(d2);
    u ^= (unsigned int)((int)u >> 31) | 0x80000000u;
    return u;
}

struct KeysU { unsigned k[16]; };

#define PIN_KEYSU(K)                                                        \
    asm("" : "+v"(K.k[0]),  "+v"(K.k[1]),  "+v"(K.k[2]),  "+v"(K.k[3]),    \
             "+v"(K.k[4]),  "+v"(K.k[5]),  "+v"(K.k[6]),  "+v"(K.k[7]),    \
             "+v"(K.k[8]),  "+v"(K.k[9]),  "+v"(K.k[10]), "+v"(K.k[11]),   \
             "+v"(K.k[12]), "+v"(K.k[13]), "+v"(K.k[14]), "+v"(K.k[15]))

__device__ __forceinline__ void initkeysu(KeysU& K, float anx, float any_, float sqn,
                                          const float4* c4, int lane) {
#pragma unroll
    for (int i = 0; i < 16; ++i) {
        const int m_ = i * 64 + lane;
        K.k[i] = topk_u(anx, any_, sqn, c4[m_]);
    }
}

__device__ __forceinline__ unsigned umin2(unsigned a, unsigned b) { return a < b ? a : b; }

__device__ __forceinline__ unsigned mintreeu(const KeysU& K) {
    return umin2(umin2(umin2(umin2(K.k[0], K.k[1]),  umin2(K.k[2], K.k[3])),
                       umin2(umin2(K.k[4], K.k[5]),  umin2(K.k[6], K.k[7]))),
                 umin2(umin2(umin2(K.k[8], K.k[9]),  umin2(K.k[10], K.k[11])),
                       umin2(umin2(K.k[12], K.k[13]), umin2(K.k[14], K.k[15]))));
}

__device__ __forceinline__ void topk_wave_body(const float* __restrict__ centers,
                                               int* __restrict__ idx_out,
                                               int tb, int tid, float4* c4) {
    const int b    = tb >> 7;          // 128 topk blocks per batch
    const int grp  = tb & 127;
    const int wave = tid >> 6;
    const int lane = tid & 63;

    // stage packed (x, y, x^2+y^2) — identical arithmetic to prior rounds
    const float4* cbase = (const float4*)(centers + (size_t)b * NN * 2);
    for (int i = tid; i < NN / 2; i += 256) {
        float4 v = cbase[i];
        c4[2 * i + 0] = make_float4(v.x, v.y, v.x * v.x + v.y * v.y, 0.f);
        c4[2 * i + 1] = make_float4(v.z, v.w, v.z * v.z + v.w * v.w, 0.f);
    }
    __syncthreads();

    const int nA = grp * 8 + wave * 2;   // two points per wave
    const int nB = nA + 1;
    const float4 cA = c4[nA];
    const float4 cB = c4[nB];

    KeysU KA, KB;
    initkeysu(KA, cA.x, cA.y, cA.z, c4, lane);
    initkeysu(KB, cB.x, cB.y, cB.z, c4, lane);
    PIN_KEYSU(KA);
    PIN_KEYSU(KB);

    unsigned lmA = mintreeu(KA);
    unsigned lmB = mintreeu(KB);
    int mmA[9], mmB[9];

#pragma unroll
    for (int r = 0; r < 9; ++r) {
        const unsigned gA = wave_min_u32_to_all(lmA);
        const unsigned gB = wave_min_u32_to_all(lmB);

        // phase 2: min m among keys equal to g (ballot -> SALU chain)
        unsigned mA = 0xffffffffu, mB = 0xffffffffu;
#pragma unroll
        for (int i = 15; i >= 0; --i) {
            unsigned long long bA = __ballot(KA.k[i] == gA);
            unsigned long long bB = __ballot(KB.k[i] == gB);
            mA = bA ? (unsigned)(i * 64) + (unsigned)__builtin_ctzll(bA) : mA;
            mB = bB ? (unsigned)(i * 64) + (unsigned)__builtin_ctzll(bB) : mB;
        }
        mmA[r] = (int)mA;
        mmB[r] = (int)mB;

        // kill exactly the winning (i, lane) key
        const unsigned iwA = mA >> 6, lwA = mA & 63;
        const unsigned iwB = mB >> 6, lwB = mB & 63;
        const bool winA = ((unsigned)lane == lwA);
        const bool winB = ((unsigned)lane == lwB);
#pragma unroll
        for (int i = 0; i < 16; ++i) {
            KA.k[i] = ((unsigned)i == iwA && winA) ? 0xffffffffu : KA.k[i];
            KB.k[i] = ((unsigned)i == iwB && winB) ? 0xffffffffu : KB.k[i];
        }
        PIN_KEYSU(KA);
        PIN_KEYSU(KB);
        lmA = mintreeu(KA);
        lmB = mintreeu(KB);
    }

    if (lane == 0) {
        int* outp = idx_out + ((size_t)b * NN + nA) * KK;   // nB rows follow
        ((int4*)outp)[0] = make_int4(mmA[1], mmA[2], mmA[3], mmA[4]);
        ((int4*)outp)[1] = make_int4(mmA[5], mmA[6], mmA[7], mmA[8]);
        ((int4*)outp)[2] = make_int4(mmB[1], mmB[2], mmB[3], mmB[4]);
        ((int4*)outp)[3] = make_int4(mmB[5], mmB[6], mmB[7], mmB[8]);
    }
}

// standalone topk dispatch (f32 fallback path)
__global__ __launch_bounds__(256) void topk_kernel(const float* __restrict__ centers,
                                                   int* __restrict__ idx_out) {
    __shared__ float4 c4[NN];
    topk_wave_body(centers, idx_out, blockIdx.x, threadIdx.x, c4);
}

// ---------------------------------------------------------------------------
// normh2: row-normalize s,t -> fp16, TWO rows per wave (the single change
// this round vs r11). r12 standalone counters: 1-row normh = 40 us @ 2.5 TB/s,
// VALUBusy 9% -> latency-bound on one serial reduce chain. 12 loads issued up
// front, 4 independent chains interleaved. Per-row fma/reduce order identical
// to rounds 6-13 -> ns/nt bit-identical.
// ---------------------------------------------------------------------------
__device__ __forceinline__ void normh2_body(const float* __restrict__ s,
                                            const float* __restrict__ t,
                                            __half* __restrict__ ns,
                                            __half* __restrict__ nt,
                                            int nb, int tid) {
    const int wave = tid >> 6;
    const int lane = tid & 63;
    const int row0 = nb * 8 + wave * 2;
    const int row1 = row0 + 1;
    const float4* s0 = (const float4*)(s + (size_t)row0 * DD);
    const float4* t0 = (const float4*)(t + (size_t)row0 * DD);
    const float4* s1 = (const float4*)(s + (size_t)row1 * DD);
    const float4* t1 = (const float4*)(t + (size_t)row1 * DD);

    float4 vs0[3], vt0[3], vs1[3], vt1[3];
#pragma unroll
    for (int i = 0; i < 3; ++i) {
        vs0[i] = s0[lane + 64 * i];
        vt0[i] = t0[lane + 64 * i];
        vs1[i] = s1[lane + 64 * i];
        vt1[i] = t1[lane + 64 * i];
    }
    float ss0 = 0.f, tt0 = 0.f, ss1 = 0.f, tt1 = 0.f;
#pragma unroll
    for (int i = 0; i < 3; ++i) {
        ss0 = fmaf(vs0[i].x, vs0[i].x, fmaf(vs0[i].y, vs0[i].y,
              fmaf(vs0[i].z, vs0[i].z, fmaf(vs0[i].w, vs0[i].w, ss0))));
        tt0 = fmaf(vt0[i].x, vt0[i].x, fmaf(vt0[i].y, vt0[i].y,
              fmaf(vt0[i].z, vt0[i].z, fmaf(vt0[i].w, vt0[i].w, tt0))));
        ss1 = fmaf(vs1[i].x, vs1[i].x, fmaf(vs1[i].y, vs1[i].y,
              fmaf(vs1[i].z, vs1[i].z, fmaf(vs1[i].w, vs1[i].w, ss1))));
        tt1 = fmaf(vt1[i].x, vt1[i].x, fmaf(vt1[i].y, vt1[i].y,
              fmaf(vt1[i].z, vt1[i].z, fmaf(vt1[i].w, vt1[i].w, tt1))));
    }
#pragma unroll
    for (int m = 1; m < 64; m <<= 1) {
        ss0 += __shfl_xor(ss0, m);
        tt0 += __shfl_xor(tt0, m);
        ss1 += __shfl_xor(ss1, m);
        tt1 += __shfl_xor(tt1, m);
    }
    const float is0 = 1.0f / fmaxf(sqrtf(ss0), EPS_F);
    const float it0 = 1.0f / fmaxf(sqrtf(tt0), EPS_F);
    const float is1 = 1.0f / fmaxf(sqrtf(ss1), EPS_F);
    const float it1 = 1.0f / fmaxf(sqrtf(tt1), EPS_F);

    uint2* ns0 = (uint2*)(ns + (size_t)row0 * DD);
    uint2* nt0 = (uint2*)(nt + (size_t)row0 * DD);
    uint2* ns1 = (uint2*)(ns + (size_t)row1 * DD);
    uint2* nt1 = (uint2*)(nt + (size_t)row1 * DD);
#pragma unroll
    for (int i = 0; i < 3; ++i) {
        __half2 a0 = __floats2half2_rn(vs0[i].x * is0, vs0[i].y * is0);
        __half2 a1 = __floats2half2_rn(vs0[i].z * is0, vs0[i].w * is0);
        __half2 b0 = __floats2half2_rn(vt0[i].x * it0, vt0[i].y * it0);
        __half2 b1 = __floats2half2_rn(vt0[i].z * it0, vt0[i].w * it0);
        __half2 c0 = __floats2half2_rn(vs1[i].x * is1, vs1[i].y * is1);
        __half2 c1 = __floats2half2_rn(vs1[i].z * is1, vs1[i].w * is1);
        __half2 d0 = __floats2half2_rn(vt1[i].x * it1, vt1[i].y * it1);
        __half2 d1 = __floats2half2_rn(vt1[i].z * it1, vt1[i].w * it1);
        uint2 ua, ub, uc, ud;
        ua.x = __builtin_bit_cast(unsigned int, a0); ua.y = __builtin_bit_cast(unsigned int, a1);
        ub.x = __builtin_bit_cast(unsigned int, b0); ub.y = __builtin_bit_cast(unsigned int, b1);
        uc.x = __builtin_bit_cast(unsigned int, c0); uc.y = __builtin_bit_cast(unsigned int, c1);
        ud.x = __builtin_bit_cast(unsigned int, d0); ud.y = __builtin_bit_cast(unsigned int, d1);
        ns0[lane + 64 * i] = ua;
        nt0[lane + 64 * i] = ub;
        ns1[lane + 64 * i] = uc;
        nt1[lane + 64 * i] = ud;
    }
}

// ---------------------------------------------------------------------------
// Fused kernel: 1:1 interleave (bid&1), 2048 topk + 2048 normh2 blocks.
// ---------------------------------------------------------------------------
__global__ __launch_bounds__(256) void fused_prep(const float* __restrict__ centers,
                                                  const float* __restrict__ s,
                                                  const float* __restrict__ t,
                                                  int* __restrict__ idx_out,
                                                  __half* __restrict__ ns,
                                                  __half* __restrict__ nt) {
    __shared__ float4 c4[NN];                 // 16 KB
    if (blockIdx.x & 1)
        normh2_body(s, t, ns, nt, blockIdx.x >> 1, threadIdx.x);
    else
        topk_wave_body(centers, idx_out, blockIdx.x >> 1, threadIdx.x, c4);
}

// ---------------------------------------------------------------------------
// lossh: gather normalized fp16 rows, dot -> cosines, smooth-L1, per-block
// partial. XCD batch-affinity swizzle. (unchanged from rounds 6-13)
// ---------------------------------------------------------------------------
__global__ __launch_bounds__(256) void lossh_kernel(const __half* __restrict__ ns,
                                                    const __half* __restrict__ nt,
                                                    const int* __restrict__ idx,
                                                    float* __restrict__ part) {
    const int bid  = blockIdx.x;
    const int v    = (bid & 7) * 512 + (bid >> 3);   // bijective, nwg%8==0
    const int wave = threadIdx.x >> 6;
    const int lane = threadIdx.x & 63;
    const int p    = v * 4 + wave;
    const int base = p & ~(NN - 1);

    int q[8];
    {
        const int4* ip = (const int4*)(idx + (size_t)p * KK);
        int4 a = ip[0], c = ip[1];
        q[0] = base + a.x; q[1] = base + a.y; q[2] = base + a.z; q[3] = base + a.w;
        q[4] = base + c.x; q[5] = base + c.y; q[6] = base + c.z; q[7] = base + c.w;
    }

    const uint2* srow = (const uint2*)(ns + (size_t)p * DD);
    const uint2* trow = (const uint2*)(nt + (size_t)p * DD);
    uint2 sa[3], ta[3];
#pragma unroll
    for (int c = 0; c < 3; ++c) {
        sa[c] = srow[lane + 64 * c];
        ta[c] = trow[lane + 64 * c];
    }

    uint2 sv[8][3], tv[8][3];
#pragma unroll
    for (int j = 0; j < 8; ++j) {
        const uint2* snb = (const uint2*)(ns + (size_t)q[j] * DD);
        const uint2* tnb = (const uint2*)(nt + (size_t)q[j] * DD);
#pragma unroll
        for (int c = 0; c < 3; ++c) {
            sv[j][c] = snb[lane + 64 * c];
            tv[j][c] = tnb[lane + 64 * c];
        }
    }

    float ds[8], dt[8];
#pragma unroll
    for (int j = 0; j < 8; ++j) {
        float a = 0.f, b = 0.f;
#pragma unroll
        for (int c = 0; c < 3; ++c) {
            a = dot4acc(sa[c], sv[j][c], a);
            b = dot4acc(ta[c], tv[j][c], b);
        }
        ds[j] = a;
        dt[j] = b;
    }
#pragma unroll
    for (int m = 1; m < 64; m <<= 1) {
#pragma unroll
        for (int j = 0; j < 8; ++j) {
            ds[j] += __shfl_xor(ds[j], m);
            dt[j] += __shfl_xor(dt[j], m);
        }
    }
    float sum = 0.f;
#pragma unroll
    for (int j = 0; j < 8; ++j) {
        const float diff = fabsf(ds[j] - dt[j]);     // rows pre-normalized
        sum += diff < BETA_F ? (0.5f * diff * diff / BETA_F) : (diff - 0.5f * BETA_F);
    }

    __shared__ float wpart[4];
    if (lane == 0) wpart[wave] = sum;
    __syncthreads();
    if (threadIdx.x == 0)
        part[v] = (wpart[0] + wpart[1]) + (wpart[2] + wpart[3]);
}

// ---------------------------------------------------------------------------
// f32 fallback path (only if ws_size too small for fp16 copies).
// ---------------------------------------------------------------------------
__global__ __launch_bounds__(256) void norm_kernel(const float* __restrict__ s,
                                                   const float* __restrict__ t,
                                                   float* __restrict__ inv_s,
                                                   float* __restrict__ inv_t) {
    const int row  = blockIdx.x * 4 + (threadIdx.x >> 6);
    const int lane = threadIdx.x & 63;
    const float4* srow = (const float4*)(s + (size_t)row * DD);
    const float4* trow = (const float4*)(t + (size_t)row * DD);
    float ss = 0.f, tt = 0.f;
#pragma unroll
    for (int i = 0; i < 3; ++i) {
        float4 v = srow[lane + 64 * i];
        ss = fmaf(v.x, v.x, fmaf(v.y, v.y, fmaf(v.z, v.z, fmaf(v.w, v.w, ss))));
        float4 w = trow[lane + 64 * i];
        tt = fmaf(w.x, w.x, fmaf(w.y, w.y, fmaf(w.z, w.z, fmaf(w.w, w.w, tt))));
    }
#pragma unroll
    for (int m = 1; m < 64; m <<= 1) {
        ss += __shfl_xor(ss, m);
        tt += __shfl_xor(tt, m);
    }
    if (lane == 0) {
        inv_s[row] = 1.0f / fmaxf(sqrtf(ss), EPS_F);
        inv_t[row] = 1.0f / fmaxf(sqrtf(tt), EPS_F);
    }
}

__global__ __launch_bounds__(256) void lossf_kernel(const float* __restrict__ s,
                                                    const float* __restrict__ t,
                                                    const int* __restrict__ idx,
                                                    const float* __restrict__ inv_s,
                                                    const float* __restrict__ inv_t,
                                                    float* __restrict__ part) {
    const int wave = threadIdx.x >> 6;
    const int lane = threadIdx.x & 63;
    const int p    = blockIdx.x * 4 + wave;
    const int base = p & ~(NN - 1);
    int q[8];
    {
        const int4* ip = (const int4*)(idx + (size_t)p * KK);
        int4 a = ip[0], c = ip[1];
        q[0] = base + a.x; q[1] = base + a.y; q[2] = base + a.z; q[3] = base + a.w;
        q[4] = base + c.x; q[5] = base + c.y; q[6] = base + c.z; q[7] = base + c.w;
    }
    float isq[8], itq[8];
#pragma unroll
    for (int j = 0; j < 8; ++j) { isq[j] = inv_s[q[j]]; itq[j] = inv_t[q[j]]; }
    const float isn = inv_s[p];
    const float itn = inv_t[p];
    const float4* srow = (const float4*)(s + (size_t)p * DD);
    const float4* trow = (const float4*)(t + (size_t)p * DD);
    float4 as0 = srow[lane], as1 = srow[lane + 64], as2 = srow[lane + 128];
    float4 at0 = trow[lane], at1 = trow[lane + 64], at2 = trow[lane + 128];
    float ds[8], dt[8];
#pragma unroll
    for (int j = 0; j < 8; ++j) {
        const float4* snb = (const float4*)(s + (size_t)q[j] * DD);
        const float4* tnb = (const float4*)(t + (size_t)q[j] * DD);
        float4 v0 = snb[lane], v1 = snb[lane + 64], v2 = snb[lane + 128];
        float4 w0 = tnb[lane], w1 = tnb[lane + 64], w2 = tnb[lane + 128];
        float a = 0.f, b = 0.f;
        a = fmaf(as0.x, v0.x, a); a = fmaf(as0.y, v0.y, a);
        a = fmaf(as0.z, v0.z, a); a = fmaf(as0.w, v0.w, a);
        a = fmaf(as1.x, v1.x, a); a = fmaf(as1.y, v1.y, a);
        a = fmaf(as1.z, v1.z, a); a = fmaf(as1.w, v1.w, a);
        a = fmaf(as2.x, v2.x, a); a = fmaf(as2.y, v2.y, a);
        a = fmaf(as2.z, v2.z, a); a = fmaf(as2.w, v2.w, a);
        b = fmaf(at0.x, w0.x, b); b = fmaf(at0.y, w0.y, b);
        b = fmaf(at0.z, w0.z, b); b = fmaf(at0.w, w0.w, b);
        b = fmaf(at1.x, w1.x, b); b = fmaf(at1.y, w1.y, b);
        b = fmaf(at1.z, w1.z, b); b = fmaf(at1.w, w1.w, b);
        b = fmaf(at2.x, w2.x, b); b = fmaf(at2.y, w2.y, b);
        b = fmaf(at2.z, w2.z, b); b = fmaf(at2.w, w2.w, b);
        ds[j] = a; dt[j] = b;
    }
#pragma unroll
    for (int m = 1; m < 64; m <<= 1) {
#pragma unroll
        for (int j = 0; j < 8; ++j) {
            ds[j] += __shfl_xor(ds[j], m);
            dt[j] += __shfl_xor(dt[j], m);
        }
    }
    float sum = 0.f;
#pragma unroll
    for (int j = 0; j < 8; ++j) {
        const float cs   = ds[j] * isn * isq[j];
        const float ct   = dt[j] * itn * itq[j];
        const float diff = fabsf(cs - ct);
        sum += diff < BETA_F ? (0.5f * diff * diff / BETA_F) : (diff - 0.5f * BETA_F);
    }
    __shared__ float wpart[4];
    if (lane == 0) wpart[wave] = sum;
    __syncthreads();
    if (threadIdx.x == 0)
        part[blockIdx.x] = (wpart[0] + wpart[1]) + (wpart[2] + wpart[3]);
}

// ---------------------------------------------------------------------------
// finalize: deterministic tree reduce of 4096 block partials + final scale.
// ---------------------------------------------------------------------------
__global__ __launch_bounds__(256) void finalize_kernel(const float* __restrict__ part,
                                                       float* __restrict__ out) {
    __shared__ float red[256];
    float acc = 0.f;
    for (int i = threadIdx.x; i < (BB * NN) / 4; i += 256) acc += part[i];
    red[threadIdx.x] = acc;
    __syncthreads();
    for (int off = 128; off > 0; off >>= 1) {
        if (threadIdx.x < off) red[threadIdx.x] += red[threadIdx.x + off];
        __syncthreads();
    }
    if (threadIdx.x == 0) out[0] = red[0] * (1.0f / (float)(BB * NN * KK));
}

extern "C" void kernel_launch(void* const* d_in, const int* in_sizes, int n_in,
                              void* d_out, int out_size, void* d_ws, size_t ws_size,
                              hipStream_t stream) {
    const float* student = (const float*)d_in[0];
    const float* teacher = (const float*)d_in[1];
    const float* centers = (const float*)d_in[2];
    float* out = (float*)d_out;

    const size_t idx_bytes  = (size_t)BB * NN * KK * sizeof(int);      // 512 KB
    const size_t half_bytes = (size_t)BB * NN * DD * sizeof(__half);   // 25.2 MB
    const size_t part_bytes = 4096 * sizeof(float);
    int* idx_buf = (int*)d_ws;

    if (ws_size >= idx_bytes + 2 * half_bytes + part_bytes) {
        __half* ns  = (__half*)((char*)d_ws + idx_bytes);
        __half* nt  = ns + (size_t)BB * NN * DD;
        float* part = (float*)((char*)d_ws + idx_bytes + 2 * half_bytes);
        fused_prep<<<TPK_BLOCKS + NORM2_BLOCKS, 256, 0, stream>>>(centers, student,
                                                                  teacher, idx_buf, ns, nt);
        lossh_kernel<<<LOSS_BLOCKS, 256, 0, stream>>>(ns, nt, idx_buf, part);
        finalize_kernel<<<1, 256, 0, stream>>>(part, out);
    } else {
        float* inv_s = (float*)((char*)d_ws + idx_bytes);
        float* inv_t = inv_s + BB * NN;
        float* part  = inv_t + BB * NN;
        topk_kernel<<<TPK_BLOCKS, 256, 0, stream>>>(centers, idx_buf);
        norm_kernel<<<LOSS_BLOCKS, 256, 0, stream>>>(student, teacher, inv_s, inv_t);
        lossf_kernel<<<LOSS_BLOCKS, 256, 0, stream>>>(student, teacher, idx_buf,
                                                      inv_s, inv_t, part);
        finalize_kernel<<<1, 256, 0, stream>>>(part, out);
    }
}

// Round 16
// 95.085 us; speedup vs baseline: 1.0591x; 1.0578x over previous
//
#include <hip/hip_runtime.h>
#include <hip/hip_fp16.h>
#include <math.h>

#define BB 16
#define NN 1024
#define DD 768
#define KK 8
#define BETA_F 0.5f
#define EPS_F 1e-8f

#define TPK4_BLOCKS ((BB * NN) / 16)       // 1024: 4 waves/block x 4 points/wave
#define NORM_BLOCKS ((BB * NN) / 4)        // 4096: 1 row/wave
#define LOSS_BLOCKS ((BB * NN) / 4)        // 4096

typedef _Float16 h2_t __attribute__((ext_vector_type(2)));

#if defined(__has_builtin)
#if __has_builtin(__builtin_amdgcn_fdot2)
#define HAVE_FDOT2 1
#endif
#endif

// acc += dot of 4 halves packed in uint2 (v_dot2_f32_f16 x2, or unpack-fma fallback)
__device__ __forceinline__ float dot4acc(uint2 a, uint2 b, float acc) {
#ifdef HAVE_FDOT2
    acc = __builtin_amdgcn_fdot2(__builtin_bit_cast(h2_t, a.x),
                                 __builtin_bit_cast(h2_t, b.x), acc, false);
    acc = __builtin_amdgcn_fdot2(__builtin_bit_cast(h2_t, a.y),
                                 __builtin_bit_cast(h2_t, b.y), acc, false);
#else
    float2 fa = __half22float2(__builtin_bit_cast(__half2, a.x));
    float2 fb = __half22float2(__builtin_bit_cast(__half2, b.x));
    acc = fmaf(fa.x, fb.x, acc); acc = fmaf(fa.y, fb.y, acc);
    fa = __half22float2(__builtin_bit_cast(__half2, a.y));
    fb = __half22float2(__builtin_bit_cast(__half2, b.y));
    acc = fmaf(fa.x, fb.x, acc); acc = fmaf(fa.y, fb.y, acc);
#endif
    return acc;
}

// ---------------------------------------------------------------------------
// Wave-wide u32 min via DPP (VALU pipe). Proven rounds 11-15.
// ---------------------------------------------------------------------------
__device__ __forceinline__ unsigned wave_min_u32_to_all(unsigned x) {
    int v = (int)x;
#define STEP(CTRL, RM) {                                                    \
        int y_ = __builtin_amdgcn_update_dpp(v, v, CTRL, RM, 0xf, false);   \
        v = (int)((unsigned)v < (unsigned)y_ ? (unsigned)v : (unsigned)y_); \
    }
    STEP(0x111, 0xf)   // row_shr:1
    STEP(0x112, 0xf)   // row_shr:2
    STEP(0x114, 0xf)   // row_shr:4
    STEP(0x118, 0xf)   // row_shr:8
    STEP(0x142, 0xa)   // row_bcast:15 -> rows 1,3
    STEP(0x143, 0xc)   // row_bcast:31 -> rows 2,3
#undef STEP
    return (unsigned)__builtin_amdgcn_readlane(v, 63);
}

// ---------------------------------------------------------------------------
// topk: exact top-9 NN, r11's proven u32 two-phase selection (DPP min value,
// 16x ballot + SALU chain for location — SALU co-issues next to VALU work).
// Change this round: FOUR independent points per wave (r12 standalone
// counters: per-wave issue duty ~5%, latency-bound -> more chains/wave).
// Selection order byte-identical to rounds 11-15 -> absmax 0.0.
// ---------------------------------------------------------------------------
__device__ __forceinline__ unsigned topk_u(float anx, float any_, float sqn, float4 c) {
    float dot = anx * c.x + any_ * c.y;
    float d2  = (sqn + c.z) - 2.0f * dot;
    unsigned int u = __float_as_uint(d2);
    u ^= (unsigned int)((int)u >> 31) | 0x80000000u;
    return u;
}

struct KeysU { unsigned k[16]; };

#define PIN_KEYSU(K)                                                        \
    asm("" : "+v"(K.k[0]),  "+v"(K.k[1]),  "+v"(K.k[2]),  "+v"(K.k[3]),    \
             "+v"(K.k[4]),  "+v"(K.k[5]),  "+v"(K.k[6]),  "+v"(K.k[7]),    \
             "+v"(K.k[8]),  "+v"(K.k[9]),  "+v"(K.k[10]), "+v"(K.k[11]),   \
             "+v"(K.k[12]), "+v"(K.k[13]), "+v"(K.k[14]), "+v"(K.k[15]))

__device__ __forceinline__ void initkeysu(KeysU& K, float anx, float any_, float sqn,
                                          const float4* c4, int lane) {
#pragma unroll
    for (int i = 0; i < 16; ++i) {
        const int m_ = i * 64 + lane;
        K.k[i] = topk_u(anx, any_, sqn, c4[m_]);
    }
}

__device__ __forceinline__ unsigned umin2(unsigned a, unsigned b) { return a < b ? a : b; }

__device__ __forceinline__ unsigned mintreeu(const KeysU& K) {
    return umin2(umin2(umin2(umin2(K.k[0], K.k[1]),  umin2(K.k[2], K.k[3])),
                       umin2(umin2(K.k[4], K.k[5]),  umin2(K.k[6], K.k[7]))),
                 umin2(umin2(umin2(K.k[8], K.k[9]),  umin2(K.k[10], K.k[11])),
                       umin2(umin2(K.k[12], K.k[13]), umin2(K.k[14], K.k[15]))));
}

__device__ __forceinline__ void topk_wave_body4(const float* __restrict__ centers,
                                                int* __restrict__ idx_out,
                                                int tb, int tid, float4* c4) {
    const int b    = tb >> 6;          // 64 topk blocks per batch
    const int grp  = tb & 63;
    const int wave = tid >> 6;
    const int lane = tid & 63;

    // stage packed (x, y, x^2+y^2) — identical arithmetic to prior rounds
    const float4* cbase = (const float4*)(centers + (size_t)b * NN * 2);
    for (int i = tid; i < NN / 2; i += 256) {
        float4 v = cbase[i];
        c4[2 * i + 0] = make_float4(v.x, v.y, v.x * v.x + v.y * v.y, 0.f);
        c4[2 * i + 1] = make_float4(v.z, v.w, v.z * v.z + v.w * v.w, 0.f);
    }
    __syncthreads();

    const int n0 = grp * 16 + wave * 4;   // four points per wave
    const float4 ca0 = c4[n0], ca1 = c4[n0 + 1], ca2 = c4[n0 + 2], ca3 = c4[n0 + 3];

    KeysU K0, K1, K2, K3;
    initkeysu(K0, ca0.x, ca0.y, ca0.z, c4, lane);
    initkeysu(K1, ca1.x, ca1.y, ca1.z, c4, lane);
    initkeysu(K2, ca2.x, ca2.y, ca2.z, c4, lane);
    initkeysu(K3, ca3.x, ca3.y, ca3.z, c4, lane);
    PIN_KEYSU(K0); PIN_KEYSU(K1); PIN_KEYSU(K2); PIN_KEYSU(K3);

    unsigned lm0 = mintreeu(K0), lm1 = mintreeu(K1);
    unsigned lm2 = mintreeu(K2), lm3 = mintreeu(K3);

    int* row0 = idx_out + ((size_t)b * NN + n0) * KK;   // 4 contiguous rows

#pragma unroll 1
    for (int r = 0; r < 9; ++r) {
        const unsigned g0 = wave_min_u32_to_all(lm0);
        const unsigned g1 = wave_min_u32_to_all(lm1);
        const unsigned g2 = wave_min_u32_to_all(lm2);
        const unsigned g3 = wave_min_u32_to_all(lm3);

        // locate: min m among keys equal to g (ballot -> SALU chain), r11 logic
        unsigned m0 = 0xffffffffu, m1 = 0xffffffffu, m2 = 0xffffffffu, m3 = 0xffffffffu;
#pragma unroll
        for (int i = 15; i >= 0; --i) {
            unsigned long long b0 = __ballot(K0.k[i] == g0);
            unsigned long long b1 = __ballot(K1.k[i] == g1);
            unsigned long long b2 = __ballot(K2.k[i] == g2);
            unsigned long long b3 = __ballot(K3.k[i] == g3);
            m0 = b0 ? (unsigned)(i * 64) + (unsigned)__builtin_ctzll(b0) : m0;
            m1 = b1 ? (unsigned)(i * 64) + (unsigned)__builtin_ctzll(b1) : m1;
            m2 = b2 ? (unsigned)(i * 64) + (unsigned)__builtin_ctzll(b2) : m2;
            m3 = b3 ? (unsigned)(i * 64) + (unsigned)__builtin_ctzll(b3) : m3;
        }

        if (r > 0 && lane == 0) {       // round 0 = self/global min, dropped
            row0[0 * KK + r - 1] = (int)m0;
            row0[1 * KK + r - 1] = (int)m1;
            row0[2 * KK + r - 1] = (int)m2;
            row0[3 * KK + r - 1] = (int)m3;
        }

        // kill exactly the winning (i, lane) key per point
        const unsigned i0 = m0 >> 6, i1 = m1 >> 6, i2 = m2 >> 6, i3 = m3 >> 6;
        const bool w0 = ((unsigned)lane == (m0 & 63));
        const bool w1 = ((unsigned)lane == (m1 & 63));
        const bool w2 = ((unsigned)lane == (m2 & 63));
        const bool w3 = ((unsigned)lane == (m3 & 63));
#pragma unroll
        for (int i = 0; i < 16; ++i) {
            K0.k[i] = ((unsigned)i == i0 && w0) ? 0xffffffffu : K0.k[i];
            K1.k[i] = ((unsigned)i == i1 && w1) ? 0xffffffffu : K1.k[i];
            K2.k[i] = ((unsigned)i == i2 && w2) ? 0xffffffffu : K2.k[i];
            K3.k[i] = ((unsigned)i == i3 && w3) ? 0xffffffffu : K3.k[i];
        }
        PIN_KEYSU(K0); PIN_KEYSU(K1); PIN_KEYSU(K2); PIN_KEYSU(K3);
        lm0 = mintreeu(K0); lm1 = mintreeu(K1);
        lm2 = mintreeu(K2); lm3 = mintreeu(K3);
    }
}

// standalone topk dispatch (f32 fallback path)
__global__ __launch_bounds__(256) void topk_kernel(const float* __restrict__ centers,
                                                   int* __restrict__ idx_out) {
    __shared__ float4 c4[NN];
    topk_wave_body4(centers, idx_out, blockIdx.x, threadIdx.x, c4);
}

// ---------------------------------------------------------------------------
// normh body: row-normalize s,t in fp32, emit normalized fp16. One wave/row.
// EXACT r11 version (part of the proven 53 us fused config).
// ---------------------------------------------------------------------------
__device__ __forceinline__ void normh_body(const float* __restrict__ s,
                                           const float* __restrict__ t,
                                           __half* __restrict__ ns,
                                           __half* __restrict__ nt,
                                           int nb, int tid) {
    const int row  = nb * 4 + (tid >> 6);
    const int lane = tid & 63;
    const float4* srow = (const float4*)(s + (size_t)row * DD);
    const float4* trow = (const float4*)(t + (size_t)row * DD);
    float4 vs[3], vt[3];
    float ss = 0.f, tt = 0.f;
#pragma unroll
    for (int i = 0; i < 3; ++i) {
        vs[i] = srow[lane + 64 * i];
        vt[i] = trow[lane + 64 * i];
        ss = fmaf(vs[i].x, vs[i].x, fmaf(vs[i].y, vs[i].y,
             fmaf(vs[i].z, vs[i].z, fmaf(vs[i].w, vs[i].w, ss))));
        tt = fmaf(vt[i].x, vt[i].x, fmaf(vt[i].y, vt[i].y,
             fmaf(vt[i].z, vt[i].z, fmaf(vt[i].w, vt[i].w, tt))));
    }
#pragma unroll
    for (int m = 1; m < 64; m <<= 1) {
        ss += __shfl_xor(ss, m);
        tt += __shfl_xor(tt, m);
    }
    const float is_ = 1.0f / fmaxf(sqrtf(ss), EPS_F);
    const float it_ = 1.0f / fmaxf(sqrtf(tt), EPS_F);

    uint2* nsrow = (uint2*)(ns + (size_t)row * DD);
    uint2* ntrow = (uint2*)(nt + (size_t)row * DD);
#pragma unroll
    for (int i = 0; i < 3; ++i) {
        __half2 a0 = __floats2half2_rn(vs[i].x * is_, vs[i].y * is_);
        __half2 a1 = __floats2half2_rn(vs[i].z * is_, vs[i].w * is_);
        __half2 b0 = __floats2half2_rn(vt[i].x * it_, vt[i].y * it_);
        __half2 b1 = __floats2half2_rn(vt[i].z * it_, vt[i].w * it_);
        uint2 ua; ua.x = __builtin_bit_cast(unsigned int, a0);
        ua.y = __builtin_bit_cast(unsigned int, a1);
        uint2 ub; ub.x = __builtin_bit_cast(unsigned int, b0);
        ub.y = __builtin_bit_cast(unsigned int, b1);
        nsrow[lane + 64 * i] = ua;
        ntrow[lane + 64 * i] = ub;
    }
}

// ---------------------------------------------------------------------------
// Fused kernel: 1 topk block per 4 normh blocks (bid%5; 5120 blocks total),
// so every CU overlaps VALU-latency-bound topk with HBM-bound normh.
// ---------------------------------------------------------------------------
__global__ __launch_bounds__(256) void fused_prep(const float* __restrict__ centers,
                                                  const float* __restrict__ s,
                                                  const float* __restrict__ t,
                                                  int* __restrict__ idx_out,
                                                  __half* __restrict__ ns,
                                                  __half* __restrict__ nt) {
    __shared__ float4 c4[NN];                 // 16 KB
    const int r5 = blockIdx.x % 5;
    const int q5 = blockIdx.x / 5;
    if (r5 == 0)
        topk_wave_body4(centers, idx_out, q5, threadIdx.x, c4);
    else
        normh_body(s, t, ns, nt, q5 * 4 + (r5 - 1), threadIdx.x);
}

// ---------------------------------------------------------------------------
// lossh: gather normalized fp16 rows, dot -> cosines, smooth-L1, per-block
// partial. XCD batch-affinity swizzle. (unchanged from rounds 6-15)
// ---------------------------------------------------------------------------
__global__ __launch_bounds__(256) void lossh_kernel(const __half* __restrict__ ns,
                                                    const __half* __restrict__ nt,
                                                    const int* __restrict__ idx,
                                                    float* __restrict__ part) {
    const int bid  = blockIdx.x;
    const int v    = (bid & 7) * 512 + (bid >> 3);   // bijective, nwg%8==0
    const int wave = threadIdx.x >> 6;
    const int lane = threadIdx.x & 63;
    const int p    = v * 4 + wave;
    const int base = p & ~(NN - 1);

    int q[8];
    {
        const int4* ip = (const int4*)(idx + (size_t)p * KK);
        int4 a = ip[0], c = ip[1];
        q[0] = base + a.x; q[1] = base + a.y; q[2] = base + a.z; q[3] = base + a.w;
        q[4] = base + c.x; q[5] = base + c.y; q[6] = base + c.z; q[7] = base + c.w;
    }

    const uint2* srow = (const uint2*)(ns + (size_t)p * DD);
    const uint2* trow = (const uint2*)(nt + (size_t)p * DD);
    uint2 sa[3], ta[3];
#pragma unroll
    for (int c = 0; c < 3; ++c) {
        sa[c] = srow[lane + 64 * c];
        ta[c] = trow[lane + 64 * c];
    }

    uint2 sv[8][3], tv[8][3];
#pragma unroll
    for (int j = 0; j < 8; ++j) {
        const uint2* snb = (const uint2*)(ns + (size_t)q[j] * DD);
        const uint2* tnb = (const uint2*)(nt + (size_t)q[j] * DD);
#pragma unroll
        for (int c = 0; c < 3; ++c) {
            sv[j][c] = snb[lane + 64 * c];
            tv[j][c] = tnb[lane + 64 * c];
        }
    }

    float ds[8], dt[8];
#pragma unroll
    for (int j = 0; j < 8; ++j) {
        float a = 0.f, b = 0.f;
#pragma unroll
        for (int c = 0; c < 3; ++c) {
            a = dot4acc(sa[c], sv[j][c], a);
            b = dot4acc(ta[c], tv[j][c], b);
        }
        ds[j] = a;
        dt[j] = b;
    }
#pragma unroll
    for (int m = 1; m < 64; m <<= 1) {
#pragma unroll
        for (int j = 0; j < 8; ++j) {
            ds[j] += __shfl_xor(ds[j], m);
            dt[j] += __shfl_xor(dt[j], m);
        }
    }
    float sum = 0.f;
#pragma unroll
    for (int j = 0; j < 8; ++j) {
        const float diff = fabsf(ds[j] - dt[j]);     // rows pre-normalized
        sum += diff < BETA_F ? (0.5f * diff * diff / BETA_F) : (diff - 0.5f * BETA_F);
    }

    __shared__ float wpart[4];
    if (lane == 0) wpart[wave] = sum;
    __syncthreads();
    if (threadIdx.x == 0)
        part[v] = (wpart[0] + wpart[1]) + (wpart[2] + wpart[3]);
}

// ---------------------------------------------------------------------------
// f32 fallback path (only if ws_size too small for fp16 copies).
// ---------------------------------------------------------------------------
__global__ __launch_bounds__(256) void norm_kernel(const float* __restrict__ s,
                                                   const float* __restrict__ t,
                                                   float* __restrict__ inv_s,
                                                   float* __restrict__ inv_t) {
    const int row  = blockIdx.x * 4 + (threadIdx.x >> 6);
    const int lane = threadIdx.x & 63;
    const float4* srow = (const float4*)(s + (size_t)row * DD);
    const float4* trow = (const float4*)(t + (size_t)row * DD);
    float ss = 0.f, tt = 0.f;
#pragma unroll
    for (int i = 0; i < 3; ++i) {
        float4 v = srow[lane + 64 * i];
        ss = fmaf(v.x, v.x, fmaf(v.y, v.y, fmaf(v.z, v.z, fmaf(v.w, v.w, ss))));
        float4 w = trow[lane + 64 * i];
        tt = fmaf(w.x, w.x, fmaf(w.y, w.y, fmaf(w.z, w.z, fmaf(w.w, w.w, tt))));
    }
#pragma unroll
    for (int m = 1; m < 64; m <<= 1) {
        ss += __shfl_xor(ss, m);
        tt += __shfl_xor(tt, m);
    }
    if (lane == 0) {
        inv_s[row] = 1.0f / fmaxf(sqrtf(ss), EPS_F);
        inv_t[row] = 1.0f / fmaxf(sqrtf(tt), EPS_F);
    }
}

__global__ __launch_bounds__(256) void lossf_kernel(const float* __restrict__ s,
                                                    const float* __restrict__ t,
                                                    const int* __restrict__ idx,
                                                    const float* __restrict__ inv_s,
                                                    const float* __restrict__ inv_t,
                                                    float* __restrict__ part) {
    const int wave = threadIdx.x >> 6;
    const int lane = threadIdx.x & 63;
    const int p    = blockIdx.x * 4 + wave;
    const int base = p & ~(NN - 1);
    int q[8];
    {
        const int4* ip = (const int4*)(idx + (size_t)p * KK);
        int4 a = ip[0], c = ip[1];
        q[0] = base + a.x; q[1] = base + a.y; q[2] = base + a.z; q[3] = base + a.w;
        q[4] = base + c.x; q[5] = base + c.y; q[6] = base + c.z; q[7] = base + c.w;
    }
    float isq[8], itq[8];
#pragma unroll
    for (int j = 0; j < 8; ++j) { isq[j] = inv_s[q[j]]; itq[j] = inv_t[q[j]]; }
    const float isn = inv_s[p];
    const float itn = inv_t[p];
    const float4* srow = (const float4*)(s + (size_t)p * DD);
    const float4* trow = (const float4*)(t + (size_t)p * DD);
    float4 as0 = srow[lane], as1 = srow[lane + 64], as2 = srow[lane + 128];
    float4 at0 = trow[lane], at1 = trow[lane + 64], at2 = trow[lane + 128];
    float ds[8], dt[8];
#pragma unroll
    for (int j = 0; j < 8; ++j) {
        const float4* snb = (const float4*)(s + (size_t)q[j] * DD);
        const float4* tnb = (const float4*)(t + (size_t)q[j] * DD);
        float4 v0 = snb[lane], v1 = snb[lane + 64], v2 = snb[lane + 128];
        float4 w0 = tnb[lane], w1 = tnb[lane + 64], w2 = tnb[lane + 128];
        float a = 0.f, b = 0.f;
        a = fmaf(as0.x, v0.x, a); a = fmaf(as0.y, v0.y, a);
        a = fmaf(as0.z, v0.z, a); a = fmaf(as0.w, v0.w, a);
        a = fmaf(as1.x, v1.x, a); a = fmaf(as1.y, v1.y, a);
        a = fmaf(as1.z, v1.z, a); a = fmaf(as1.w, v1.w, a);
        a = fmaf(as2.x, v2.x, a); a = fmaf(as2.y, v2.y, a);
        a = fmaf(as2.z, v2.z, a); a = fmaf(as2.w, v2.w, a);
        b = fmaf(at0.x, w0.x, b); b = fmaf(at0.y, w0.y, b);
        b = fmaf(at0.z, w0.z, b); b = fmaf(at0.w, w0.w, b);
        b = fmaf(at1.x, w1.x, b); b = fmaf(at1.y, w1.y, b);
        b = fmaf(at1.z, w1.z, b); b = fmaf(at1.w, w1.w, b);
        b = fmaf(at2.x, w2.x, b); b = fmaf(at2.y, w2.y, b);
        b = fmaf(at2.z, w2.z, b); b = fmaf(at2.w, w2.w, b);
        ds[j] = a; dt[j] = b;
    }
#pragma unroll
    for (int m = 1; m < 64; m <<= 1) {
#pragma unroll
        for (int j = 0; j < 8; ++j) {
            ds[j] += __shfl_xor(ds[j], m);
            dt[j] += __shfl_xor(dt[j], m);
        }
    }
    float sum = 0.f;
#pragma unroll
    for (int j = 0; j < 8; ++j) {
        const float cs   = ds[j] * isn * isq[j];
        const float ct   = dt[j] * itn * itq[j];
        const float diff = fabsf(cs - ct);
        sum += diff < BETA_F ? (0.5f * diff * diff / BETA_F) : (diff - 0.5f * BETA_F);
    }
    __shared__ float wpart[4];
    if (lane == 0) wpart[wave] = sum;
    __syncthreads();
    if (threadIdx.x == 0)
        part[blockIdx.x] = (wpart[0] + wpart[1]) + (wpart[2] + wpart[3]);
}

// ---------------------------------------------------------------------------
// finalize: deterministic tree reduce of 4096 block partials + final scale.
// ---------------------------------------------------------------------------
__global__ __launch_bounds__(256) void finalize_kernel(const float* __restrict__ part,
                                                       float* __restrict__ out) {
    __shared__ float red[256];
    float acc = 0.f;
    for (int i = threadIdx.x; i < (BB * NN) / 4; i += 256) acc += part[i];
    red[threadIdx.x] = acc;
    __syncthreads();
    for (int off = 128; off > 0; off >>= 1) {
        if (threadIdx.x < off) red[threadIdx.x] += red[threadIdx.x + off];
        __syncthreads();
    }
    if (threadIdx.x == 0) out[0] = red[0] * (1.0f / (float)(BB * NN * KK));
}

extern "C" void kernel_launch(void* const* d_in, const int* in_sizes, int n_in,
                              void* d_out, int out_size, void* d_ws, size_t ws_size,
                              hipStream_t stream) {
    const float* student = (const float*)d_in[0];
    const float* teacher = (const float*)d_in[1];
    const float* centers = (const float*)d_in[2];
    float* out = (float*)d_out;

    const size_t idx_bytes  = (size_t)BB * NN * KK * sizeof(int);      // 512 KB
    const size_t half_bytes = (size_t)BB * NN * DD * sizeof(__half);   // 25.2 MB
    const size_t part_bytes = 4096 * sizeof(float);
    int* idx_buf = (int*)d_ws;

    if (ws_size >= idx_bytes + 2 * half_bytes + part_bytes) {
        __half* ns  = (__half*)((char*)d_ws + idx_bytes);
        __half* nt  = ns + (size_t)BB * NN * DD;
        float* part = (float*)((char*)d_ws + idx_bytes + 2 * half_bytes);
        fused_prep<<<TPK4_BLOCKS + NORM_BLOCKS, 256, 0, stream>>>(centers, student,
                                                                  teacher, idx_buf, ns, nt);
        lossh_kernel<<<LOSS_BLOCKS, 256, 0, stream>>>(ns, nt, idx_buf, part);
        finalize_kernel<<<1, 256, 0, stream>>>(part, out);
    } else {
        float* inv_s = (float*)((char*)d_ws + idx_bytes);
        float* inv_t = inv_s + BB * NN;
        float* part  = inv_t + BB * NN;
        topk_kernel<<<TPK4_BLOCKS, 256, 0, stream>>>(centers, idx_buf);
        norm_kernel<<<NORM_BLOCKS, 256, 0, stream>>>(student, teacher, inv_s, inv_t);
        lossf_kernel<<<LOSS_BLOCKS, 256, 0, stream>>>(student, teacher, idx_buf,
                                                      inv_s, inv_t, part);
        finalize_kernel<<<1, 256, 0, stream>>>(part, out);
    }
}

// Round 17
// 81.802 us; speedup vs baseline: 1.2311x; 1.1624x over previous
//
#include <hip/hip_runtime.h>
#include <hip/hip_fp16.h>
#include <math.h>

#define BB 16
#define NN 1024
#define DD 768
#define KK 8
#define BETA_F 0.5f
#define EPS_F 1e-8f

#define TPK_BLOCKS ((BB * NN) / 8)         // 2048: 4 waves/block x 2 points/wave
#define NORM_BLOCKS ((BB * NN) / 4)        // 4096

typedef _Float16 h2_t __attribute__((ext_vector_type(2)));

#if defined(__has_builtin)
#if __has_builtin(__builtin_amdgcn_fdot2)
#define HAVE_FDOT2 1
#endif
#endif

// acc += dot of 4 halves packed in uint2 (v_dot2_f32_f16 x2, or unpack-fma fallback)
__device__ __forceinline__ float dot4acc(uint2 a, uint2 b, float acc) {
#ifdef HAVE_FDOT2
    acc = __builtin_amdgcn_fdot2(__builtin_bit_cast(h2_t, a.x),
                                 __builtin_bit_cast(h2_t, b.x), acc, false);
    acc = __builtin_amdgcn_fdot2(__builtin_bit_cast(h2_t, a.y),
                                 __builtin_bit_cast(h2_t, b.y), acc, false);
#else
    float2 fa = __half22float2(__builtin_bit_cast(__half2, a.x));
    float2 fb = __half22float2(__builtin_bit_cast(__half2, b.x));
    acc = fmaf(fa.x, fb.x, acc); acc = fmaf(fa.y, fb.y, acc);
    fa = __half22float2(__builtin_bit_cast(__half2, a.y));
    fb = __half22float2(__builtin_bit_cast(__half2, b.y));
    acc = fmaf(fa.x, fb.x, acc); acc = fmaf(fa.y, fb.y, acc);
#endif
    return acc;
}

// ---------------------------------------------------------------------------
// Wave-wide u32 min via DPP (VALU pipe, 1-cyc-issue v_min_u32). Proven.
// ---------------------------------------------------------------------------
__device__ __forceinline__ unsigned wave_min_u32_to_all(unsigned x) {
    int v = (int)x;
#define STEP(CTRL, RM) {                                                    \
        int y_ = __builtin_amdgcn_update_dpp(v, v, CTRL, RM, 0xf, false);   \
        v = (int)((unsigned)v < (unsigned)y_ ? (unsigned)v : (unsigned)y_); \
    }
    STEP(0x111, 0xf)   // row_shr:1
    STEP(0x112, 0xf)   // row_shr:2
    STEP(0x114, 0xf)   // row_shr:4
    STEP(0x118, 0xf)   // row_shr:8
    STEP(0x142, 0xa)   // row_bcast:15 -> rows 1,3
    STEP(0x143, 0xc)   // row_bcast:31 -> rows 2,3
#undef STEP
    return (unsigned)__builtin_amdgcn_readlane(v, 63);
}

// ---------------------------------------------------------------------------
// topk: exact top-9 NN, wave-wide 9-round min extraction, TWO-PHASE u32:
//   phase 1: g = wave-min of u (monotone-uint32 of d2)
//   phase 2: winning m = min{ i*64+lane : k[i]==g } via 16x ballot + SALU
//            descending-i cselect/ctz chain (scalar pipe, co-issues free).
// Lexicographic (u, m) min — selection bit-identical to all passing rounds.
// Two independent points per wave. BEST MEASURED CONFIG (r11: 53 us fused).
// ---------------------------------------------------------------------------
__device__ __forceinline__ unsigned topk_u(float anx, float any_, float sqn, float4 c) {
    float dot = anx * c.x + any_ * c.y;
    float d2  = (sqn + c.z) - 2.0f * dot;
    unsigned int u = __float_as_uint(d2);
    u ^= (unsigned int)((int)u >> 31) | 0x80000000u;
    return u;
}

struct KeysU { unsigned k[16]; };

// zero-cost: force the 16 key u32s into arch VGPRs (blocks AGPR/scratch demotion)
#define PIN_KEYSU(K)                                                        \
    asm("" : "+v"(K.k[0]),  "+v"(K.k[1]),  "+v"(K.k[2]),  "+v"(K.k[3]),    \
             "+v"(K.k[4]),  "+v"(K.k[5]),  "+v"(K.k[6]),  "+v"(K.k[7]),    \
             "+v"(K.k[8]),  "+v"(K.k[9]),  "+v"(K.k[10]), "+v"(K.k[11]),   \
             "+v"(K.k[12]), "+v"(K.k[13]), "+v"(K.k[14]), "+v"(K.k[15]))

__device__ __forceinline__ void initkeysu(KeysU& K, float anx, float any_, float sqn,
                                          const float4* c4, int lane) {
#pragma unroll
    for (int i = 0; i < 16; ++i) {
        const int m_ = i * 64 + lane;
        K.k[i] = topk_u(anx, any_, sqn, c4[m_]);
    }
}

__device__ __forceinline__ unsigned umin2(unsigned a, unsigned b) { return a < b ? a : b; }

__device__ __forceinline__ unsigned mintreeu(const KeysU& K) {
    return umin2(umin2(umin2(umin2(K.k[0], K.k[1]),  umin2(K.k[2], K.k[3])),
                       umin2(umin2(K.k[4], K.k[5]),  umin2(K.k[6], K.k[7]))),
                 umin2(umin2(umin2(K.k[8], K.k[9]),  umin2(K.k[10], K.k[11])),
                       umin2(umin2(K.k[12], K.k[13]), umin2(K.k[14], K.k[15]))));
}

__device__ __forceinline__ void topk_wave_body(const float* __restrict__ centers,
                                               int* __restrict__ idx_out,
                                               int tb, int tid, float4* c4) {
    const int b    = tb >> 7;          // 128 topk blocks per batch
    const int grp  = tb & 127;
    const int wave = tid >> 6;
    const int lane = tid & 63;

    // stage packed (x, y, x^2+y^2) — identical arithmetic to prior rounds
    const float4* cbase = (const float4*)(centers + (size_t)b * NN * 2);
    for (int i = tid; i < NN / 2; i += 256) {
        float4 v = cbase[i];
        c4[2 * i + 0] = make_float4(v.x, v.y, v.x * v.x + v.y * v.y, 0.f);
        c4[2 * i + 1] = make_float4(v.z, v.w, v.z * v.z + v.w * v.w, 0.f);
    }
    __syncthreads();

    const int nA = grp * 8 + wave * 2;   // two points per wave
    const int nB = nA + 1;
    const float4 cA = c4[nA];
    const float4 cB = c4[nB];

    KeysU KA, KB;
    initkeysu(KA, cA.x, cA.y, cA.z, c4, lane);
    initkeysu(KB, cB.x, cB.y, cB.z, c4, lane);
    PIN_KEYSU(KA);
    PIN_KEYSU(KB);

    unsigned lmA = mintreeu(KA);
    unsigned lmB = mintreeu(KB);
    int mmA[9], mmB[9];

#pragma unroll
    for (int r = 0; r < 9; ++r) {
        const unsigned gA = wave_min_u32_to_all(lmA);
        const unsigned gB = wave_min_u32_to_all(lmB);

        // phase 2: min m among keys equal to g (ballot -> SALU chain)
        unsigned mA = 0xffffffffu, mB = 0xffffffffu;
#pragma unroll
        for (int i = 15; i >= 0; --i) {
            unsigned long long bA = __ballot(KA.k[i] == gA);
            unsigned long long bB = __ballot(KB.k[i] == gB);
            mA = bA ? (unsigned)(i * 64) + (unsigned)__builtin_ctzll(bA) : mA;
            mB = bB ? (unsigned)(i * 64) + (unsigned)__builtin_ctzll(bB) : mB;
        }
        mmA[r] = (int)mA;
        mmB[r] = (int)mB;

        // kill exactly the winning (i, lane) key
        const unsigned iwA = mA >> 6, lwA = mA & 63;
        const unsigned iwB = mB >> 6, lwB = mB & 63;
        const bool winA = ((unsigned)lane == lwA);
        const bool winB = ((unsigned)lane == lwB);
#pragma unroll
        for (int i = 0; i < 16; ++i) {
            KA.k[i] = ((unsigned)i == iwA && winA) ? 0xffffffffu : KA.k[i];
            KB.k[i] = ((unsigned)i == iwB && winB) ? 0xffffffffu : KB.k[i];
        }
        PIN_KEYSU(KA);
        PIN_KEYSU(KB);
        lmA = mintreeu(KA);
        lmB = mintreeu(KB);
    }

    if (lane == 0) {
        int* outp = idx_out + ((size_t)b * NN + nA) * KK;   // nB rows follow
        ((int4*)outp)[0] = make_int4(mmA[1], mmA[2], mmA[3], mmA[4]);
        ((int4*)outp)[1] = make_int4(mmA[5], mmA[6], mmA[7], mmA[8]);
        ((int4*)outp)[2] = make_int4(mmB[1], mmB[2], mmB[3], mmB[4]);
        ((int4*)outp)[3] = make_int4(mmB[5], mmB[6], mmB[7], mmB[8]);
    }
}

// ---------------------------------------------------------------------------
// normh body: row-normalize s,t in fp32, emit normalized fp16. One wave/row.
// ---------------------------------------------------------------------------
__device__ __forceinline__ void normh_body(const float* __restrict__ s,
                                           const float* __restrict__ t,
                                           __half* __restrict__ ns,
                                           __half* __restrict__ nt,
                                           int nb, int tid) {
    const int row  = nb * 4 + (tid >> 6);
    const int lane = tid & 63;
    const float4* srow = (const float4*)(s + (size_t)row * DD);
    const float4* trow = (const float4*)(t + (size_t)row * DD);
    float4 vs[3], vt[3];
    float ss = 0.f, tt = 0.f;
#pragma unroll
    for (int i = 0; i < 3; ++i) {
        vs[i] = srow[lane + 64 * i];
        vt[i] = trow[lane + 64 * i];
        ss = fmaf(vs[i].x, vs[i].x, fmaf(vs[i].y, vs[i].y,
             fmaf(vs[i].z, vs[i].z, fmaf(vs[i].w, vs[i].w, ss))));
        tt = fmaf(vt[i].x, vt[i].x, fmaf(vt[i].y, vt[i].y,
             fmaf(vt[i].z, vt[i].z, fmaf(vt[i].w, vt[i].w, tt))));
    }
#pragma unroll
    for (int m = 1; m < 64; m <<= 1) {
        ss += __shfl_xor(ss, m);
        tt += __shfl_xor(tt, m);
    }
    const float is_ = 1.0f / fmaxf(sqrtf(ss), EPS_F);
    const float it_ = 1.0f / fmaxf(sqrtf(tt), EPS_F);

    uint2* nsrow = (uint2*)(ns + (size_t)row * DD);
    uint2* ntrow = (uint2*)(nt + (size_t)row * DD);
#pragma unroll
    for (int i = 0; i < 3; ++i) {
        __half2 a0 = __floats2half2_rn(vs[i].x * is_, vs[i].y * is_);
        __half2 a1 = __floats2half2_rn(vs[i].z * is_, vs[i].w * is_);
        __half2 b0 = __floats2half2_rn(vt[i].x * it_, vt[i].y * it_);
        __half2 b1 = __floats2half2_rn(vt[i].z * it_, vt[i].w * it_);
        uint2 ua; ua.x = __builtin_bit_cast(unsigned int, a0);
        ua.y = __builtin_bit_cast(unsigned int, a1);
        uint2 ub; ub.x = __builtin_bit_cast(unsigned int, b0);
        ub.y = __builtin_bit_cast(unsigned int, b1);
        nsrow[lane + 64 * i] = ua;
        ntrow[lane + 64 * i] = ub;
    }
}

// ---------------------------------------------------------------------------
// Fused kernel: 1 topk block per 2 normh blocks (bid%3), so every CU overlaps
// VALU-bound topk with HBM-bound normh from t=0. LDS 16 KB.
// ---------------------------------------------------------------------------
__global__ __launch_bounds__(256) void fused_prep(const float* __restrict__ centers,
                                                  const float* __restrict__ s,
                                                  const float* __restrict__ t,
                                                  int* __restrict__ idx_out,
                                                  __half* __restrict__ ns,
                                                  __half* __restrict__ nt) {
    __shared__ float4 c4[NN];                 // 16 KB
    const int r3 = blockIdx.x % 3;
    const int q3 = blockIdx.x / 3;
    if (r3 == 0)
        topk_wave_body(centers, idx_out, q3, threadIdx.x, c4);
    else
        normh_body(s, t, ns, nt, q3 * 2 + (r3 - 1), threadIdx.x);
}

// standalone topk for the f32 fallback path
__global__ __launch_bounds__(256) void topk_kernel(const float* __restrict__ centers,
                                                   int* __restrict__ idx_out) {
    __shared__ float4 c4[NN];
    topk_wave_body(centers, idx_out, blockIdx.x, threadIdx.x, c4);
}

// ---------------------------------------------------------------------------
// lossh: gather normalized fp16 rows, dot -> cosines, smooth-L1, per-block
// partial. XCD batch-affinity swizzle.
// ---------------------------------------------------------------------------
__global__ __launch_bounds__(256) void lossh_kernel(const __half* __restrict__ ns,
                                                    const __half* __restrict__ nt,
                                                    const int* __restrict__ idx,
                                                    float* __restrict__ part) {
    const int bid  = blockIdx.x;
    const int v    = (bid & 7) * 512 + (bid >> 3);   // bijective, nwg%8==0
    const int wave = threadIdx.x >> 6;
    const int lane = threadIdx.x & 63;
    const int p    = v * 4 + wave;
    const int base = p & ~(NN - 1);

    int q[8];
    {
        const int4* ip = (const int4*)(idx + (size_t)p * KK);
        int4 a = ip[0], c = ip[1];
        q[0] = base + a.x; q[1] = base + a.y; q[2] = base + a.z; q[3] = base + a.w;
        q[4] = base + c.x; q[5] = base + c.y; q[6] = base + c.z; q[7] = base + c.w;
    }

    const uint2* srow = (const uint2*)(ns + (size_t)p * DD);
    const uint2* trow = (const uint2*)(nt + (size_t)p * DD);
    uint2 sa[3], ta[3];
#pragma unroll
    for (int c = 0; c < 3; ++c) {
        sa[c] = srow[lane + 64 * c];
        ta[c] = trow[lane + 64 * c];
    }

    uint2 sv[8][3], tv[8][3];
#pragma unroll
    for (int j = 0; j < 8; ++j) {
        const uint2* snb = (const uint2*)(ns + (size_t)q[j] * DD);
        const uint2* tnb = (const uint2*)(nt + (size_t)q[j] * DD);
#pragma unroll
        for (int c = 0; c < 3; ++c) {
            sv[j][c] = snb[lane + 64 * c];
            tv[j][c] = tnb[lane + 64 * c];
        }
    }

    float ds[8], dt[8];
#pragma unroll
    for (int j = 0; j < 8; ++j) {
        float a = 0.f, b = 0.f;
#pragma unroll
        for (int c = 0; c < 3; ++c) {
            a = dot4acc(sa[c], sv[j][c], a);
            b = dot4acc(ta[c], tv[j][c], b);
        }
        ds[j] = a;
        dt[j] = b;
    }
#pragma unroll
    for (int m = 1; m < 64; m <<= 1) {
#pragma unroll
        for (int j = 0; j < 8; ++j) {
            ds[j] += __shfl_xor(ds[j], m);
            dt[j] += __shfl_xor(dt[j], m);
        }
    }
    float sum = 0.f;
#pragma unroll
    for (int j = 0; j < 8; ++j) {
        const float diff = fabsf(ds[j] - dt[j]);     // rows pre-normalized
        sum += diff < BETA_F ? (0.5f * diff * diff / BETA_F) : (diff - 0.5f * BETA_F);
    }

    __shared__ float wpart[4];
    if (lane == 0) wpart[wave] = sum;
    __syncthreads();
    if (threadIdx.x == 0)
        part[v] = (wpart[0] + wpart[1]) + (wpart[2] + wpart[3]);
}

// ---------------------------------------------------------------------------
// f32 fallback path (only if ws_size too small for fp16 copies).
// ---------------------------------------------------------------------------
__global__ __launch_bounds__(256) void norm_kernel(const float* __restrict__ s,
                                                   const float* __restrict__ t,
                                                   float* __restrict__ inv_s,
                                                   float* __restrict__ inv_t) {
    const int row  = blockIdx.x * 4 + (threadIdx.x >> 6);
    const int lane = threadIdx.x & 63;
    const float4* srow = (const float4*)(s + (size_t)row * DD);
    const float4* trow = (const float4*)(t + (size_t)row * DD);
    float ss = 0.f, tt = 0.f;
#pragma unroll
    for (int i = 0; i < 3; ++i) {
        float4 v = srow[lane + 64 * i];
        ss = fmaf(v.x, v.x, fmaf(v.y, v.y, fmaf(v.z, v.z, fmaf(v.w, v.w, ss))));
        float4 w = trow[lane + 64 * i];
        tt = fmaf(w.x, w.x, fmaf(w.y, w.y, fmaf(w.z, w.z, fmaf(w.w, w.w, tt))));
    }
#pragma unroll
    for (int m = 1; m < 64; m <<= 1) {
        ss += __shfl_xor(ss, m);
        tt += __shfl_xor(tt, m);
    }
    if (lane == 0) {
        inv_s[row] = 1.0f / fmaxf(sqrtf(ss), EPS_F);
        inv_t[row] = 1.0f / fmaxf(sqrtf(tt), EPS_F);
    }
}

__global__ __launch_bounds__(256) void lossf_kernel(const float* __restrict__ s,
                                                    const float* __restrict__ t,
                                                    const int* __restrict__ idx,
                                                    const float* __restrict__ inv_s,
                                                    const float* __restrict__ inv_t,
                                                    float* __restrict__ part) {
    const int wave = threadIdx.x >> 6;
    const int lane = threadIdx.x & 63;
    const int p    = blockIdx.x * 4 + wave;
    const int base = p & ~(NN - 1);
    int q[8];
    {
        const int4* ip = (const int4*)(idx + (size_t)p * KK);
        int4 a = ip[0], c = ip[1];
        q[0] = base + a.x; q[1] = base + a.y; q[2] = base + a.z; q[3] = base + a.w;
        q[4] = base + c.x; q[5] = base + c.y; q[6] = base + c.z; q[7] = base + c.w;
    }
    float isq[8], itq[8];
#pragma unroll
    for (int j = 0; j < 8; ++j) { isq[j] = inv_s[q[j]]; itq[j] = inv_t[q[j]]; }
    const float isn = inv_s[p];
    const float itn = inv_t[p];
    const float4* srow = (const float4*)(s + (size_t)p * DD);
    const float4* trow = (const float4*)(t + (size_t)p * DD);
    float4 as0 = srow[lane], as1 = srow[lane + 64], as2 = srow[lane + 128];
    float4 at0 = trow[lane], at1 = trow[lane + 64], at2 = trow[lane + 128];
    float ds[8], dt[8];
#pragma unroll
    for (int j = 0; j < 8; ++j) {
        const float4* snb = (const float4*)(s + (size_t)q[j] * DD);
        const float4* tnb = (const float4*)(t + (size_t)q[j] * DD);
        float4 v0 = snb[lane], v1 = snb[lane + 64], v2 = snb[lane + 128];
        float4 w0 = tnb[lane], w1 = tnb[lane + 64], w2 = tnb[lane + 128];
        float a = 0.f, b = 0.f;
        a = fmaf(as0.x, v0.x, a); a = fmaf(as0.y, v0.y, a);
        a = fmaf(as0.z, v0.z, a); a = fmaf(as0.w, v0.w, a);
        a = fmaf(as1.x, v1.x, a); a = fmaf(as1.y, v1.y, a);
        a = fmaf(as1.z, v1.z, a); a = fmaf(as1.w, v1.w, a);
        a = fmaf(as2.x, v2.x, a); a = fmaf(as2.y, v2.y, a);
        a = fmaf(as2.z, v2.z, a); a = fmaf(as2.w, v2.w, a);
        b = fmaf(at0.x, w0.x, b); b = fmaf(at0.y, w0.y, b);
        b = fmaf(at0.z, w0.z, b); b = fmaf(at0.w, w0.w, b);
        b = fmaf(at1.x, w1.x, b); b = fmaf(at1.y, w1.y, b);
        b = fmaf(at1.z, w1.z, b); b = fmaf(at1.w, w1.w, b);
        b = fmaf(at2.x, w2.x, b); b = fmaf(at2.y, w2.y, b);
        b = fmaf(at2.z, w2.z, b); b = fmaf(at2.w, w2.w, b);
        ds[j] = a; dt[j] = b;
    }
#pragma unroll
    for (int m = 1; m < 64; m <<= 1) {
#pragma unroll
        for (int j = 0; j < 8; ++j) {
            ds[j] += __shfl_xor(ds[j], m);
            dt[j] += __shfl_xor(dt[j], m);
        }
    }
    float sum = 0.f;
#pragma unroll
    for (int j = 0; j < 8; ++j) {
        const float cs   = ds[j] * isn * isq[j];
        const float ct   = dt[j] * itn * itq[j];
        const float diff = fabsf(cs - ct);
        sum += diff < BETA_F ? (0.5f * diff * diff / BETA_F) : (diff - 0.5f * BETA_F);
    }
    __shared__ float wpart[4];
    if (lane == 0) wpart[wave] = sum;
    __syncthreads();
    if (threadIdx.x == 0)
        part[blockIdx.x] = (wpart[0] + wpart[1]) + (wpart[2] + wpart[3]);
}

// ---------------------------------------------------------------------------
// finalize: deterministic tree reduce of 4096 block partials + final scale.
// ---------------------------------------------------------------------------
__global__ __launch_bounds__(256) void finalize_kernel(const float* __restrict__ part,
                                                       float* __restrict__ out) {
    __shared__ float red[256];
    float acc = 0.f;
    for (int i = threadIdx.x; i < (BB * NN) / 4; i += 256) acc += part[i];
    red[threadIdx.x] = acc;
    __syncthreads();
    for (int off = 128; off > 0; off >>= 1) {
        if (threadIdx.x < off) red[threadIdx.x] += red[threadIdx.x + off];
        __syncthreads();
    }
    if (threadIdx.x == 0) out[0] = red[0] * (1.0f / (float)(BB * NN * KK));
}

extern "C" void kernel_launch(void* const* d_in, const int* in_sizes, int n_in,
                              void* d_out, int out_size, void* d_ws, size_t ws_size,
                              hipStream_t stream) {
    const float* student = (const float*)d_in[0];
    const float* teacher = (const float*)d_in[1];
    const float* centers = (const float*)d_in[2];
    float* out = (float*)d_out;

    const size_t idx_bytes  = (size_t)BB * NN * KK * sizeof(int);      // 512 KB
    const size_t half_bytes = (size_t)BB * NN * DD * sizeof(__half);   // 25.2 MB
    const size_t part_bytes = 4096 * sizeof(float);
    int* idx_buf = (int*)d_ws;

    if (ws_size >= idx_bytes + 2 * half_bytes + part_bytes) {
        __half* ns  = (__half*)((char*)d_ws + idx_bytes);
        __half* nt  = ns + (size_t)BB * NN * DD;
        float* part = (float*)((char*)d_ws + idx_bytes + 2 * half_bytes);
        fused_prep<<<TPK_BLOCKS + NORM_BLOCKS, 256, 0, stream>>>(centers, student,
                                                                 teacher, idx_buf, ns, nt);
        lossh_kernel<<<NORM_BLOCKS, 256, 0, stream>>>(ns, nt, idx_buf, part);
        finalize_kernel<<<1, 256, 0, stream>>>(part, out);
    } else {
        float* inv_s = (float*)((char*)d_ws + idx_bytes);
        float* inv_t = inv_s + BB * NN;
        float* part  = inv_t + BB * NN;
        topk_kernel<<<TPK_BLOCKS, 256, 0, stream>>>(centers, idx_buf);
        norm_kernel<<<NORM_BLOCKS, 256, 0, stream>>>(student, teacher, inv_s, inv_t);
        lossf_kernel<<<NORM_BLOCKS, 256, 0, stream>>>(student, teacher, idx_buf,
                                                      inv_s, inv_t, part);
        finalize_kernel<<<1, 256, 0, stream>>>(part, out);
    }
}